// Round 6
// baseline (298.829 us; speedup 1.0000x reference)
//
#include <hip/hip_runtime.h>
#include <math.h>

#define N_NODES 50000
#define N_EDGES 800000
#define IN_F    256
#define HID_F   128
#define OUT_F   40
#define W0N     (3*HID_F)   // 384
#define W1N     (3*OUT_F)   // 120

// k_prep block ranges
#define XB   6250                        // x convert: 12.8M elems / (256*8)
#define P0B  ((IN_F * W0N) / 256)        // 384
#define P1B  ((HID_F * W1N) / 256)       // 60
#define CB0  (XB + P0B + P1B)            // 6694
#define CNTB ((N_EDGES + 255) / 256)     // 3125
#define PREPB (CB0 + CNTB)               // 9819

typedef __attribute__((ext_vector_type(8))) unsigned short ushort8;
typedef __attribute__((ext_vector_type(4))) unsigned short ushort4v;
typedef __attribute__((ext_vector_type(8))) __bf16 bf16x8;
typedef __attribute__((ext_vector_type(4))) float f32x4;
typedef __attribute__((ext_vector_type(2))) float f32x2;

static __device__ __forceinline__ float sigmoidf_(float x) {
    return 1.0f / (1.0f + expf(-x));
}

static __device__ __forceinline__ unsigned short f2bf(float f) {
    unsigned u = __float_as_uint(f);
    u += 0x7FFFu + ((u >> 16) & 1u);
    return (unsigned short)(u >> 16);
}

static __device__ __forceinline__ float bflo(unsigned u) { return __uint_as_float(u << 16); }
static __device__ __forceinline__ float bfhi(unsigned u) { return __uint_as_float(u & 0xffff0000u); }

// ------- fused prep: x->bf16 | pack W0^T | pack W1^T(k-perm) | count+rank+rc -------

__global__ __launch_bounds__(256) void k_prep(
        const float* __restrict__ x, unsigned short* __restrict__ xb,
        const float* __restrict__ Wl0, const float* __restrict__ Wh0,
        const float* __restrict__ Wm0, unsigned short* __restrict__ W0t,
        const float* __restrict__ Wl1, const float* __restrict__ Wh1,
        const float* __restrict__ Wm1, unsigned short* __restrict__ W1t,
        const int* __restrict__ ei, int* __restrict__ deg,
        unsigned short* __restrict__ rank, unsigned* __restrict__ rc) {
    int b = blockIdx.x, t = threadIdx.x;
    if (b < XB) {
        size_t idx = (size_t)b * 2048 + t * 8;
        float4 f0 = *(const float4*)(x + idx);
        float4 f1 = *(const float4*)(x + idx + 4);
        ushort8 u;
        u[0]=f2bf(f0.x); u[1]=f2bf(f0.y); u[2]=f2bf(f0.z); u[3]=f2bf(f0.w);
        u[4]=f2bf(f1.x); u[5]=f2bf(f1.y); u[6]=f2bf(f1.z); u[7]=f2bf(f1.w);
        *(ushort8*)(xb + idx) = u;
    } else if (b < XB + P0B) {
        int i = (b - XB) * 256 + t;
        int n = i / IN_F, k = i % IN_F;
        float v;
        if (n < HID_F)            v = Wl0[k * HID_F + n];
        else if (n < 2 * HID_F)   v = Wh0[k * HID_F + (n - HID_F)];
        else                      v = Wm0[k * HID_F + (n - 2 * HID_F)];
        W0t[i] = f2bf(v);
    } else if (b < CB0) {
        int i = (b - XB - P0B) * 256 + t;
        int n = i / HID_F, kp = i % HID_F;
        // k-dim permuted to match hbuf's permuted layout: feat = g*64 + q*16 + c
        int k = ((kp >> 6) << 6) + ((kp & 3) << 4) + ((kp >> 2) & 15);
        float v;
        if (n < OUT_F)            v = Wl1[k * OUT_F + n];
        else if (n < 2 * OUT_F)   v = Wh1[k * OUT_F + (n - OUT_F)];
        else                      v = Wm1[k * OUT_F + (n - 2 * OUT_F)];
        W1t[i] = f2bf(v);
    } else {
        int e = (b - CB0) * 256 + t;
        if (e < N_EDGES) {
            int r = ei[e];
            int c = ei[N_EDGES + e];
            int old = atomicAdd(&deg[r], 1);
            rank[e] = (unsigned short)old;
            rc[e] = ((unsigned)r << 16) | (unsigned)c;
        }
    }
}

// ------- single-block scan: rowPtr (exclusive) + dinv, 1024 threads -------

#define SCH 49   // 1024*49 >= 50000

__global__ __launch_bounds__(1024) void k_scan_all(
        const int* __restrict__ deg, int* __restrict__ rowPtr,
        float* __restrict__ dinv) {
    __shared__ int s[1024];
    int t = threadIdx.x;
    int start = t * SCH;
    int end = min(start + SCH, N_NODES);
    int sum = 0;
    for (int g = start; g < end; ++g) {
        int v = deg[g];
        dinv[g] = 1.0f / (1.0f + (float)v);
        sum += v;
    }
    s[t] = sum; __syncthreads();
    for (int d = 1; d < 1024; d <<= 1) {
        int x = (t >= d) ? s[t - d] : 0;
        __syncthreads();
        s[t] += x;
        __syncthreads();
    }
    int base = s[t] - sum;   // exclusive prefix
    for (int g = start; g < end; ++g) {
        rowPtr[g] = base;
        base += deg[g];
    }
    if (t == 1023) rowPtr[N_NODES] = N_EDGES;
}

// ---------------- bf16 MFMA GEMM + optional fused CSR-fill ----------------
// tile 128x128, BK=32, 4 waves (2x2).
// EPI=0: plain bf16 split write: cols [0,nsplit)->C0(ld0), rest->C1(ld1).
// EPI=1: layer-0 write: Hs (bf16 perm), Hq (fp8 perm), HmP (bf16 perm).
//   permuted pos within 64-col group: pos = col*4 + n  <->  feat = n*16 + col

#define BKP 40   // 32 + 8 pad

template<int EPI>
__global__ __launch_bounds__(256) void k_gemm_fill(
        const unsigned short* __restrict__ A, const unsigned short* __restrict__ Bt,
        unsigned short* __restrict__ C0, int ld0,
        unsigned short* __restrict__ C1, int ld1, int nsplit,
        unsigned short* __restrict__ Hs, unsigned char* __restrict__ Hq,
        unsigned short* __restrict__ HmP,
        int M, int N, int K, int nxt,
        const unsigned* __restrict__ rc, const unsigned short* __restrict__ rank,
        const int* __restrict__ rowPtr, unsigned short* __restrict__ colIdx) {
    __shared__ unsigned short As[128 * BKP];
    __shared__ unsigned short Bs[128 * BKP];
    int tid  = threadIdx.x;

    if ((int)blockIdx.x >= nxt) {
        int fid = (blockIdx.x - nxt) * gridDim.y + blockIdx.y;
        int e = fid * 256 + tid;
        if (e < N_EDGES) {
            unsigned x = rc[e];
            int r = (int)(x >> 16);
            int pos = rowPtr[r] + (int)rank[e];
            colIdx[pos] = (unsigned short)(x & 0xffffu);
        }
        return;
    }

    int lane = tid & 63, wid = tid >> 6;
    int wr = wid >> 1, wc = wid & 1;
    int bm = blockIdx.y * 128, bn = blockIdx.x * 128;

    int srow = tid >> 1;
    int scol = (tid & 1) * 16;

    int garow = min(bm + srow, M - 1);
    int gbrow = min(bn + srow, N - 1);

    f32x4 acc[4][4];
#pragma unroll
    for (int m = 0; m < 4; ++m)
#pragma unroll
        for (int n = 0; n < 4; ++n)
            acc[m][n] = (f32x4)(0.0f);

    int kg = (lane >> 4) * 8;
    int rA = wr * 64 + (lane & 15);
    int rB = wc * 64 + (lane & 15);

    for (int k0 = 0; k0 < K; k0 += 32) {
        {
            const unsigned short* src = A + (size_t)garow * K + k0 + scol;
            *(ushort8*)&As[srow * BKP + scol]     = *(const ushort8*)(src);
            *(ushort8*)&As[srow * BKP + scol + 8] = *(const ushort8*)(src + 8);
        }
        {
            const unsigned short* src = Bt + (size_t)gbrow * K + k0 + scol;
            *(ushort8*)&Bs[srow * BKP + scol]     = *(const ushort8*)(src);
            *(ushort8*)&Bs[srow * BKP + scol + 8] = *(const ushort8*)(src + 8);
        }
        __syncthreads();

        bf16x8 a[4], b[4];
#pragma unroll
        for (int m = 0; m < 4; ++m)
            a[m] = __builtin_bit_cast(bf16x8, *(const ushort8*)&As[(rA + m * 16) * BKP + kg]);
#pragma unroll
        for (int n = 0; n < 4; ++n)
            b[n] = __builtin_bit_cast(bf16x8, *(const ushort8*)&Bs[(rB + n * 16) * BKP + kg]);
#pragma unroll
        for (int m = 0; m < 4; ++m)
#pragma unroll
            for (int n = 0; n < 4; ++n)
                acc[m][n] = __builtin_amdgcn_mfma_f32_16x16x32_bf16(a[m], b[n], acc[m][n], 0, 0, 0);
        __syncthreads();
    }

    int col  = lane & 15;
    int rsub = (lane >> 4) * 4;

    if (EPI == 0) {
#pragma unroll
        for (int m = 0; m < 4; ++m) {
            int gm0 = bm + wr * 64 + m * 16 + rsub;
#pragma unroll
            for (int n = 0; n < 4; ++n) {
                int gn = bn + wc * 64 + n * 16 + col;
                if (gn >= N) continue;
#pragma unroll
                for (int j = 0; j < 4; ++j) {
                    int gm = gm0 + j;
                    if (gm >= M) continue;
                    unsigned short b = f2bf(acc[m][n][j]);
                    if (gn < nsplit) C0[(size_t)gm * ld0 + gn] = b;
                    else             C1[(size_t)gm * ld1 + (gn - nsplit)] = b;
                }
            }
        }
    } else {
        // permuted writes; this thread covers pos base = bn + wc*64 + col*4
#pragma unroll
        for (int m = 0; m < 4; ++m) {
            int gm0 = bm + wr * 64 + m * 16 + rsub;
#pragma unroll
            for (int j = 0; j < 4; ++j) {
                int gm = gm0 + j;
                if (gm >= M) continue;
                float v0 = acc[m][0][j], v1 = acc[m][1][j];
                float v2 = acc[m][2][j], v3 = acc[m][3][j];
                ushort4v o;
                o[0] = f2bf(v0); o[1] = f2bf(v1); o[2] = f2bf(v2); o[3] = f2bf(v3);
                if (bn < 256) {
                    int pos = bn + wc * 64 + col * 4;
                    *(ushort4v*)&Hs[(size_t)gm * 256 + pos] = o;
                    int pk = 0;
                    pk = __builtin_amdgcn_cvt_pk_fp8_f32(v0, v1, pk, false);
                    pk = __builtin_amdgcn_cvt_pk_fp8_f32(v2, v3, pk, true);
                    *(unsigned*)&Hq[(size_t)gm * 256 + pos] = (unsigned)pk;
                } else {
                    int pos = wc * 64 + col * 4;
                    *(ushort4v*)&HmP[(size_t)gm * 128 + pos] = o;
                }
            }
        }
    }
}

// ---------------- layer 0: wave-per-node, fp8 neighbor gather + ACM epilogue ----------------
// Hq fp8 perm [256 B/row]; Hs bf16 perm [256]; HmP bf16 perm [128].
// lane's 4 true feats: c_q = (lane>>4)*64 + q*16 + (lane&15); lanes<32 = hl, >=32 = hh.

__global__ __launch_bounds__(256) void k_layer0(
        const unsigned short* __restrict__ Hs, const unsigned char* __restrict__ Hq,
        const unsigned short* __restrict__ HmP,
        const int* __restrict__ rowPtr, const unsigned short* __restrict__ colIdx,
        const float* __restrict__ dinv,
        const float* __restrict__ al, const float* __restrict__ ah,
        const float* __restrict__ am, const float* __restrict__ att,
        unsigned short* __restrict__ hout) {
    int lane = threadIdx.x & 63;
    int i = blockIdx.x * 4 + (threadIdx.x >> 6);

    int p0 = rowPtr[i], p1 = rowPtr[i + 1];
    float a0 = 0.f, a1 = 0.f, a2 = 0.f, a3 = 0.f;
    int off4 = lane * 4;
    int p = p0;
    for (; p + 7 < p1; p += 8) {
        int j[8];
#pragma unroll
        for (int q = 0; q < 8; ++q) j[q] = (int)colIdx[p + q];
        unsigned w[8];
#pragma unroll
        for (int q = 0; q < 8; ++q) w[q] = *(const unsigned*)(Hq + (size_t)j[q] * 256 + off4);
#pragma unroll
        for (int q = 0; q < 8; ++q) {
            f32x2 d0 = __builtin_amdgcn_cvt_pk_f32_fp8((int)w[q], false);
            f32x2 d1 = __builtin_amdgcn_cvt_pk_f32_fp8((int)w[q], true);
            a0 += d0.x; a1 += d0.y; a2 += d1.x; a3 += d1.y;
        }
    }
    for (; p < p1; ++p) {
        int j = (int)colIdx[p];
        unsigned w = *(const unsigned*)(Hq + (size_t)j * 256 + off4);
        f32x2 d0 = __builtin_amdgcn_cvt_pk_f32_fp8((int)w, false);
        f32x2 d1 = __builtin_amdgcn_cvt_pk_f32_fp8((int)w, true);
        a0 += d0.x; a1 += d0.y; a2 += d1.x; a3 += d1.y;
    }

    uint2 sv = *(const uint2*)(Hs + (size_t)i * 256 + off4);   // 4 bf16 self vals
    float s0 = bflo(sv.x), s1 = bfhi(sv.x), s2 = bflo(sv.y), s3 = bfhi(sv.y);
    float di = dinv[i];
    float l0 = di * (s0 + a0), l1 = di * (s1 + a1);
    float l2 = di * (s2 + a2), l3 = di * (s3 + a3);

    float ol0 = fmaxf(l0, 0.f), ol1 = fmaxf(l1, 0.f);
    float ol2 = fmaxf(l2, 0.f), ol3 = fmaxf(l3, 0.f);
    float oh0 = fmaxf(s0 - l0, 0.f), oh1 = fmaxf(s1 - l1, 0.f);
    float oh2 = fmaxf(s2 - l2, 0.f), oh3 = fmaxf(s3 - l3, 0.f);

    int c0 = ((lane >> 4) << 6) + (lane & 15);   // true feat of q=0

    float om0 = 0.f, om1 = 0.f, om2 = 0.f, om3 = 0.f;
    float prA, prM = 0.f;
    if (lane < 32) {
        uint2 hv = *(const uint2*)(HmP + (size_t)i * 128 + off4);
        om0 = fmaxf(bflo(hv.x), 0.f); om1 = fmaxf(bfhi(hv.x), 0.f);
        om2 = fmaxf(bflo(hv.y), 0.f); om3 = fmaxf(bfhi(hv.y), 0.f);
        prA = ol0 * al[c0] + ol1 * al[c0 + 16] + ol2 * al[c0 + 32] + ol3 * al[c0 + 48];
        prM = om0 * am[c0] + om1 * am[c0 + 16] + om2 * am[c0 + 32] + om3 * am[c0 + 48];
    } else {
        int ch = c0 - 128;
        prA = oh0 * ah[ch] + oh1 * ah[ch + 16] + oh2 * ah[ch + 32] + oh3 * ah[ch + 48];
    }

#pragma unroll
    for (int d = 1; d < 32; d <<= 1) prA += __shfl_xor(prA, d);
#pragma unroll
    for (int d = 1; d < 32; d <<= 1) prM += __shfl_xor(prM, d);
    float g0 = __shfl(prA, 0);
    float g1 = __shfl(prA, 32);
    float g2 = __shfl(prM, 0);

    float sg0 = sigmoidf_(g0), sg1 = sigmoidf_(g1), sg2 = sigmoidf_(g2);
    const float inv3 = (1.0f / 3.0f);
    float e0 = (sg0 * att[0] + sg1 * att[3] + sg2 * att[6]) * inv3;
    float e1 = (sg0 * att[1] + sg1 * att[4] + sg2 * att[7]) * inv3;
    float e2 = (sg0 * att[2] + sg1 * att[5] + sg2 * att[8]) * inv3;
    float mx = fmaxf(e0, fmaxf(e1, e2));
    float x0 = expf(e0 - mx), x1 = expf(e1 - mx), x2 = expf(e2 - mx);
    float inv = 1.0f / (x0 + x1 + x2);
    float c0f = 3.0f * inv * x0, c1f = 3.0f * inv * x1, c2f = 3.0f * inv * x2;

    int src = lane | 32;
    float th0 = __shfl(oh0, src), th1 = __shfl(oh1, src);
    float th2 = __shfl(oh2, src), th3 = __shfl(oh3, src);

    if (lane < 32) {
        // hbuf permuted: pos p = lane*4+q -> true feat c_q (matches W1t k-perm)
        ushort4v o;
        o[0] = f2bf(c0f * ol0 + c1f * th0 + c2f * om0);
        o[1] = f2bf(c0f * ol1 + c1f * th1 + c2f * om1);
        o[2] = f2bf(c0f * ol2 + c1f * th2 + c2f * om2);
        o[3] = f2bf(c0f * ol3 + c1f * th3 + c2f * om3);
        *(ushort4v*)&hout[(size_t)i * 128 + off4] = o;
    }
}

// ---------------- layer 1: wave-per-node aggregate + ACM epilogue ----------------
// H1g[i][c] bf16: c<40 hl, c>=40 hh (80 cols). H1m: hm (40). lanes 0..39 active.

__global__ __launch_bounds__(256) void k_layer1(
        const unsigned short* __restrict__ H1g, const unsigned short* __restrict__ H1m,
        const int* __restrict__ rowPtr, const unsigned short* __restrict__ colIdx,
        const float* __restrict__ dinv,
        const float* __restrict__ al, const float* __restrict__ ah,
        const float* __restrict__ am, const float* __restrict__ att,
        float* __restrict__ out) {
    int lane = threadIdx.x & 63;
    int i = blockIdx.x * 4 + (threadIdx.x >> 6);

    int p0 = rowPtr[i], p1 = rowPtr[i + 1];
    float a0 = 0.f, a1 = 0.f;
    int off = lane * 2;
    bool active = lane < 40;
    int p = p0;
    if (active) {
        for (; p + 7 < p1; p += 8) {
            int j[8];
#pragma unroll
            for (int q = 0; q < 8; ++q) j[q] = (int)colIdx[p + q];
            unsigned v[8];
#pragma unroll
            for (int q = 0; q < 8; ++q) v[q] = *(const unsigned*)(H1g + (size_t)j[q] * 80 + off);
#pragma unroll
            for (int q = 0; q < 8; ++q) { a0 += bflo(v[q]); a1 += bfhi(v[q]); }
        }
        for (; p < p1; ++p) {
            int j = (int)colIdx[p];
            unsigned v = *(const unsigned*)(H1g + (size_t)j * 80 + off);
            a0 += bflo(v); a1 += bfhi(v);
        }
    }

    float s0 = 0.f, s1 = 0.f;
    if (active) {
        unsigned sv = *(const unsigned*)(H1g + (size_t)i * 80 + off);
        s0 = bflo(sv); s1 = bfhi(sv);
    }
    float di = dinv[i];
    float l0 = di * (s0 + a0), l1 = di * (s1 + a1);

    float ol0 = fmaxf(l0, 0.f), ol1 = fmaxf(l1, 0.f);
    float oh0 = fmaxf(s0 - l0, 0.f), oh1 = fmaxf(s1 - l1, 0.f);

    float om0 = 0.f, om1 = 0.f;
    float r0 = 0.f, r1 = 0.f, r2 = 0.f;
    if (lane < 20) {
        unsigned hv = *(const unsigned*)(H1m + (size_t)i * 40 + off);
        om0 = fmaxf(bflo(hv), 0.f); om1 = fmaxf(bfhi(hv), 0.f);
        float2 alv = *(const float2*)(al + off);
        float2 amv = *(const float2*)(am + off);
        r0 = ol0 * alv.x + ol1 * alv.y;
        r2 = om0 * amv.x + om1 * amv.y;
    } else if (lane < 40) {
        float2 ahv = *(const float2*)(ah + (off - 40));
        r1 = oh0 * ahv.x + oh1 * ahv.y;
    }

#pragma unroll
    for (int d = 1; d < 64; d <<= 1) r0 += __shfl_xor(r0, d);
#pragma unroll
    for (int d = 1; d < 64; d <<= 1) r1 += __shfl_xor(r1, d);
#pragma unroll
    for (int d = 1; d < 64; d <<= 1) r2 += __shfl_xor(r2, d);

    float sg0 = sigmoidf_(r0), sg1 = sigmoidf_(r1), sg2 = sigmoidf_(r2);
    const float inv3 = (1.0f / 3.0f);
    float e0 = (sg0 * att[0] + sg1 * att[3] + sg2 * att[6]) * inv3;
    float e1 = (sg0 * att[1] + sg1 * att[4] + sg2 * att[7]) * inv3;
    float e2 = (sg0 * att[2] + sg1 * att[5] + sg2 * att[8]) * inv3;
    float mx = fmaxf(e0, fmaxf(e1, e2));
    float x0 = expf(e0 - mx), x1 = expf(e1 - mx), x2 = expf(e2 - mx);
    float inv = 1.0f / (x0 + x1 + x2);
    float c0 = 3.0f * inv * x0, c1 = 3.0f * inv * x1, c2 = 3.0f * inv * x2;

    int src = (lane + 20) & 63;
    float th0 = __shfl(oh0, src), th1 = __shfl(oh1, src);

    if (lane < 20) {
        float2 o;
        o.x = c0 * ol0 + c1 * th0 + c2 * om0;
        o.y = c0 * ol1 + c1 * th1 + c2 * om1;
        *(float2*)&out[(size_t)i * 40 + off] = o;
    }
}

// ---------------- launch ----------------

extern "C" void kernel_launch(void* const* d_in, const int* in_sizes, int n_in,
                              void* d_out, int out_size, void* d_ws, size_t ws_size,
                              hipStream_t stream) {
    const float* x    = (const float*)d_in[0];
    const int*   ei   = (const int*)d_in[1];
    const float* Wl0  = (const float*)d_in[2];
    const float* Wh0  = (const float*)d_in[3];
    const float* Wm0  = (const float*)d_in[4];
    const float* al0  = (const float*)d_in[5];
    const float* ah0  = (const float*)d_in[6];
    const float* am0  = (const float*)d_in[7];
    const float* att0 = (const float*)d_in[8];
    const float* Wl1  = (const float*)d_in[9];
    const float* Wh1  = (const float*)d_in[10];
    const float* Wm1  = (const float*)d_in[11];
    const float* al1  = (const float*)d_in[12];
    const float* ah1  = (const float*)d_in[13];
    const float* am1  = (const float*)d_in[14];
    const float* att1 = (const float*)d_in[15];
    float* out = (float*)d_out;

    char* ws = (char*)d_ws;
    size_t off = 0;
    auto alloc = [&](size_t bytes) -> char* {
        char* p = ws + off;
        off += (bytes + 255) & ~(size_t)255;
        return p;
    };
    int*   deg    = (int*)  alloc((size_t)N_NODES * 4);
    int*   rowPtr = (int*)  alloc((size_t)(N_NODES + 1) * 4);
    unsigned short* rank   = (unsigned short*)alloc((size_t)N_EDGES * 2);
    unsigned*       rc     = (unsigned*)      alloc((size_t)N_EDGES * 4);
    unsigned short* colIdx = (unsigned short*)alloc((size_t)N_EDGES * 2);
    float* dinv   = (float*)alloc((size_t)N_NODES * 4);
    unsigned short* W0t  = (unsigned short*)alloc((size_t)W0N * IN_F * 2);
    unsigned short* W1t  = (unsigned short*)alloc((size_t)W1N * HID_F * 2);
    unsigned short* xb   = (unsigned short*)alloc((size_t)N_NODES * IN_F * 2);
    unsigned short* Hs   = (unsigned short*)alloc((size_t)N_NODES * 256 * 2);
    unsigned char*  Hq   = (unsigned char*) alloc((size_t)N_NODES * 256);
    unsigned short* HmP  = (unsigned short*)alloc((size_t)N_NODES * 128 * 2);
    unsigned short* H1g  = (unsigned short*)alloc((size_t)N_NODES * 80 * 2);
    unsigned short* H1m  = (unsigned short*)alloc((size_t)N_NODES * 40 * 2);
    unsigned short* hbuf = (unsigned short*)alloc((size_t)N_NODES * HID_F * 2);

    // 1. zero deg
    hipMemsetAsync(deg, 0, (size_t)N_NODES * 4, stream);
    // 2. fused prep (x->bf16, W packs, degree count + rank + rc)
    k_prep<<<PREPB, 256, 0, stream>>>(x, xb, Wl0, Wh0, Wm0, W0t,
                                      Wl1, Wh1, Wm1, W1t, ei, deg, rank, rc);
    // 3. single-block scan (rowPtr + dinv)
    k_scan_all<<<1, 1024, 0, stream>>>(deg, rowPtr, dinv);
    // 4. GEMM0 (layer-0 epilogue: Hs/Hq/HmP) with fused atomic-free CSR fill
    {
        dim3 grid(3 + 8, (N_NODES + 127) / 128);
        k_gemm_fill<1><<<grid, 256, 0, stream>>>(xb, W0t,
                                                 nullptr, 0, nullptr, 0, 0,
                                                 Hs, Hq, HmP,
                                                 N_NODES, W0N, IN_F, 3,
                                                 rc, rank, rowPtr, colIdx);
    }
    // 5. layer-0 aggregate + epilogue
    k_layer0<<<N_NODES / 4, 256, 0, stream>>>(Hs, Hq, HmP, rowPtr, colIdx, dinv,
                                              al0, ah0, am0, att0, hbuf);
    // 6. GEMM1 (plain epilogue -> H1g/H1m)
    {
        dim3 grid(1, (N_NODES + 127) / 128);
        k_gemm_fill<0><<<grid, 256, 0, stream>>>(hbuf, W1t,
                                                 H1g, 80, H1m, 40, 80,
                                                 nullptr, nullptr, nullptr,
                                                 N_NODES, W1N, HID_F, 1,
                                                 nullptr, nullptr, nullptr, nullptr);
    }
    // 7. layer-1 aggregate + epilogue
    k_layer1<<<N_NODES / 4, 256, 0, stream>>>(H1g, H1m, rowPtr, colIdx, dinv,
                                              al1, ah1, am1, att1, out);
}

// Round 7
// 213.537 us; speedup vs baseline: 1.3994x; 1.3994x over previous
//
#include <hip/hip_runtime.h>
#include <math.h>

#define N_NODES 50000
#define N_EDGES 800000
#define IN_F    256
#define HID_F   128
#define OUT_F   40
#define W0N     (3*HID_F)   // 384
#define W1N     (3*OUT_F)   // 120
#define NB      ((N_NODES + 255) / 256)   // 196

// k_prep block ranges
#define XB   6250                        // x convert: 12.8M elems / (256*8)
#define P0B  ((IN_F * W0N) / 256)        // 384
#define P1B  ((HID_F * W1N) / 256)       // 60
#define CB0  (XB + P0B + P1B)            // 6694
#define CNTB ((N_EDGES + 255) / 256)     // 3125
#define PREPB (CB0 + CNTB)               // 9819

typedef __attribute__((ext_vector_type(8))) unsigned short ushort8;
typedef __attribute__((ext_vector_type(4))) unsigned short ushort4v;
typedef __attribute__((ext_vector_type(8))) __bf16 bf16x8;
typedef __attribute__((ext_vector_type(4))) float f32x4;
typedef __attribute__((ext_vector_type(2))) float f32x2;

static __device__ __forceinline__ float sigmoidf_(float x) {
    return 1.0f / (1.0f + expf(-x));
}

static __device__ __forceinline__ unsigned short f2bf(float f) {
    unsigned u = __float_as_uint(f);
    u += 0x7FFFu + ((u >> 16) & 1u);
    return (unsigned short)(u >> 16);
}

static __device__ __forceinline__ float bflo(unsigned u) { return __uint_as_float(u << 16); }
static __device__ __forceinline__ float bfhi(unsigned u) { return __uint_as_float(u & 0xffff0000u); }

// ------- fused prep: x->bf16 | pack W0^T | pack W1^T(k-perm) | count+rank+rc -------

__global__ __launch_bounds__(256) void k_prep(
        const float* __restrict__ x, unsigned short* __restrict__ xb,
        const float* __restrict__ Wl0, const float* __restrict__ Wh0,
        const float* __restrict__ Wm0, unsigned short* __restrict__ W0t,
        const float* __restrict__ Wl1, const float* __restrict__ Wh1,
        const float* __restrict__ Wm1, unsigned short* __restrict__ W1t,
        const int* __restrict__ ei, int* __restrict__ deg,
        unsigned short* __restrict__ rank, unsigned* __restrict__ rc) {
    int b = blockIdx.x, t = threadIdx.x;
    if (b < XB) {
        size_t idx = (size_t)b * 2048 + t * 8;
        float4 f0 = *(const float4*)(x + idx);
        float4 f1 = *(const float4*)(x + idx + 4);
        ushort8 u;
        u[0]=f2bf(f0.x); u[1]=f2bf(f0.y); u[2]=f2bf(f0.z); u[3]=f2bf(f0.w);
        u[4]=f2bf(f1.x); u[5]=f2bf(f1.y); u[6]=f2bf(f1.z); u[7]=f2bf(f1.w);
        *(ushort8*)(xb + idx) = u;
    } else if (b < XB + P0B) {
        int i = (b - XB) * 256 + t;
        int n = i / IN_F, k = i % IN_F;
        float v;
        if (n < HID_F)            v = Wl0[k * HID_F + n];
        else if (n < 2 * HID_F)   v = Wh0[k * HID_F + (n - HID_F)];
        else                      v = Wm0[k * HID_F + (n - 2 * HID_F)];
        W0t[i] = f2bf(v);
    } else if (b < CB0) {
        int i = (b - XB - P0B) * 256 + t;
        int n = i / HID_F, kp = i % HID_F;
        // k-dim permuted to match hbuf's permuted layout: feat = g*64 + q*16 + c
        int k = ((kp >> 6) << 6) + ((kp & 3) << 4) + ((kp >> 2) & 15);
        float v;
        if (n < OUT_F)            v = Wl1[k * OUT_F + n];
        else if (n < 2 * OUT_F)   v = Wh1[k * OUT_F + (n - OUT_F)];
        else                      v = Wm1[k * OUT_F + (n - 2 * OUT_F)];
        W1t[i] = f2bf(v);
    } else {
        int e = (b - CB0) * 256 + t;
        if (e < N_EDGES) {
            int r = ei[e];
            int c = ei[N_EDGES + e];
            int old = atomicAdd(&deg[r], 1);
            rank[e] = (unsigned short)old;
            rc[e] = ((unsigned)r << 16) | (unsigned)c;
        }
    }
}

// ---------------- CSR scan (multi-block, 3 kernels) ----------------

__global__ void k_scan1(const int* __restrict__ deg, int* __restrict__ rowPtr,
                        int* __restrict__ blkTot, float* __restrict__ dinv) {
    __shared__ int s[256];
    int t = threadIdx.x;
    int gid = blockIdx.x * 256 + t;
    int v = (gid < N_NODES) ? deg[gid] : 0;
    if (gid < N_NODES) dinv[gid] = 1.0f / (1.0f + (float)v);
    s[t] = v; __syncthreads();
    for (int d = 1; d < 256; d <<= 1) {
        int x = (t >= d) ? s[t - d] : 0;
        __syncthreads();
        s[t] += x;
        __syncthreads();
    }
    if (gid < N_NODES) rowPtr[gid] = s[t];
    if (t == 255) blkTot[blockIdx.x] = s[255];
}

__global__ void k_scan2(int* __restrict__ blk) {
    __shared__ int s[256];
    int t = threadIdx.x;
    int v = (t < NB) ? blk[t] : 0;
    s[t] = v; __syncthreads();
    for (int d = 1; d < 256; d <<= 1) {
        int x = (t >= d) ? s[t - d] : 0;
        __syncthreads();
        s[t] += x;
        __syncthreads();
    }
    if (t < NB) blk[t] = s[t] - v;
}

__global__ void k_scan3(const int* __restrict__ deg, const int* __restrict__ blkOff,
                        int* __restrict__ rowPtr) {
    int t = threadIdx.x;
    int gid = blockIdx.x * 256 + t;
    if (gid < N_NODES) rowPtr[gid] += blkOff[blockIdx.x] - deg[gid];
    if (gid == 0) rowPtr[N_NODES] = N_EDGES;
}

// ---------------- bf16 MFMA GEMM + optional fused CSR-fill ----------------
// tile 128x128, BK=32, 4 waves (2x2).
// EPI=0: plain bf16 split write: cols [0,nsplit)->C0(ld0), rest->C1(ld1).
// EPI=1: layer-0 write: Hs (bf16 perm), Hq (fp8 perm), HmP (bf16 perm).
//   permuted pos within 64-col group: pos = col*4 + n  <->  feat = n*16 + col

#define BKP 40   // 32 + 8 pad

template<int EPI>
__global__ __launch_bounds__(256) void k_gemm_fill(
        const unsigned short* __restrict__ A, const unsigned short* __restrict__ Bt,
        unsigned short* __restrict__ C0, int ld0,
        unsigned short* __restrict__ C1, int ld1, int nsplit,
        unsigned short* __restrict__ Hs, unsigned char* __restrict__ Hq,
        unsigned short* __restrict__ HmP,
        int M, int N, int K, int nxt,
        const unsigned* __restrict__ rc, const unsigned short* __restrict__ rank,
        const int* __restrict__ rowPtr, unsigned short* __restrict__ colIdx) {
    __shared__ unsigned short As[128 * BKP];
    __shared__ unsigned short Bs[128 * BKP];
    int tid  = threadIdx.x;

    if ((int)blockIdx.x >= nxt) {
        int fid = (blockIdx.x - nxt) * gridDim.y + blockIdx.y;
        int e = fid * 256 + tid;
        if (e < N_EDGES) {
            unsigned x = rc[e];
            int r = (int)(x >> 16);
            int pos = rowPtr[r] + (int)rank[e];
            colIdx[pos] = (unsigned short)(x & 0xffffu);
        }
        return;
    }

    int lane = tid & 63, wid = tid >> 6;
    int wr = wid >> 1, wc = wid & 1;
    int bm = blockIdx.y * 128, bn = blockIdx.x * 128;

    int srow = tid >> 1;
    int scol = (tid & 1) * 16;

    int garow = min(bm + srow, M - 1);
    int gbrow = min(bn + srow, N - 1);

    f32x4 acc[4][4];
#pragma unroll
    for (int m = 0; m < 4; ++m)
#pragma unroll
        for (int n = 0; n < 4; ++n)
            acc[m][n] = (f32x4)(0.0f);

    int kg = (lane >> 4) * 8;
    int rA = wr * 64 + (lane & 15);
    int rB = wc * 64 + (lane & 15);

    for (int k0 = 0; k0 < K; k0 += 32) {
        {
            const unsigned short* src = A + (size_t)garow * K + k0 + scol;
            *(ushort8*)&As[srow * BKP + scol]     = *(const ushort8*)(src);
            *(ushort8*)&As[srow * BKP + scol + 8] = *(const ushort8*)(src + 8);
        }
        {
            const unsigned short* src = Bt + (size_t)gbrow * K + k0 + scol;
            *(ushort8*)&Bs[srow * BKP + scol]     = *(const ushort8*)(src);
            *(ushort8*)&Bs[srow * BKP + scol + 8] = *(const ushort8*)(src + 8);
        }
        __syncthreads();

        bf16x8 a[4], b[4];
#pragma unroll
        for (int m = 0; m < 4; ++m)
            a[m] = __builtin_bit_cast(bf16x8, *(const ushort8*)&As[(rA + m * 16) * BKP + kg]);
#pragma unroll
        for (int n = 0; n < 4; ++n)
            b[n] = __builtin_bit_cast(bf16x8, *(const ushort8*)&Bs[(rB + n * 16) * BKP + kg]);
#pragma unroll
        for (int m = 0; m < 4; ++m)
#pragma unroll
            for (int n = 0; n < 4; ++n)
                acc[m][n] = __builtin_amdgcn_mfma_f32_16x16x32_bf16(a[m], b[n], acc[m][n], 0, 0, 0);
        __syncthreads();
    }

    int col  = lane & 15;
    int rsub = (lane >> 4) * 4;

    if (EPI == 0) {
#pragma unroll
        for (int m = 0; m < 4; ++m) {
            int gm0 = bm + wr * 64 + m * 16 + rsub;
#pragma unroll
            for (int n = 0; n < 4; ++n) {
                int gn = bn + wc * 64 + n * 16 + col;
                if (gn >= N) continue;
#pragma unroll
                for (int j = 0; j < 4; ++j) {
                    int gm = gm0 + j;
                    if (gm >= M) continue;
                    unsigned short b = f2bf(acc[m][n][j]);
                    if (gn < nsplit) C0[(size_t)gm * ld0 + gn] = b;
                    else             C1[(size_t)gm * ld1 + (gn - nsplit)] = b;
                }
            }
        }
    } else {
        // permuted writes; this thread covers pos base = bn + wc*64 + col*4
#pragma unroll
        for (int m = 0; m < 4; ++m) {
            int gm0 = bm + wr * 64 + m * 16 + rsub;
#pragma unroll
            for (int j = 0; j < 4; ++j) {
                int gm = gm0 + j;
                if (gm >= M) continue;
                float v0 = acc[m][0][j], v1 = acc[m][1][j];
                float v2 = acc[m][2][j], v3 = acc[m][3][j];
                ushort4v o;
                o[0] = f2bf(v0); o[1] = f2bf(v1); o[2] = f2bf(v2); o[3] = f2bf(v3);
                if (bn < 256) {
                    int pos = bn + wc * 64 + col * 4;
                    *(ushort4v*)&Hs[(size_t)gm * 256 + pos] = o;
                    int pk = 0;
                    pk = __builtin_amdgcn_cvt_pk_fp8_f32(v0, v1, pk, false);
                    pk = __builtin_amdgcn_cvt_pk_fp8_f32(v2, v3, pk, true);
                    *(unsigned*)&Hq[(size_t)gm * 256 + pos] = (unsigned)pk;
                } else {
                    int pos = wc * 64 + col * 4;
                    *(ushort4v*)&HmP[(size_t)gm * 128 + pos] = o;
                }
            }
        }
    }
}

// ---------------- layer 0: wave-per-node, fp8 neighbor gather + ACM epilogue ----------------
// Hq fp8 perm [256 B/row]; Hs bf16 perm [256]; HmP bf16 perm [128].
// lane's 4 true feats: c_q = (lane>>4)*64 + q*16 + (lane&15); lanes<32 = hl, >=32 = hh.

__global__ __launch_bounds__(256) void k_layer0(
        const unsigned short* __restrict__ Hs, const unsigned char* __restrict__ Hq,
        const unsigned short* __restrict__ HmP,
        const int* __restrict__ rowPtr, const unsigned short* __restrict__ colIdx,
        const float* __restrict__ dinv,
        const float* __restrict__ al, const float* __restrict__ ah,
        const float* __restrict__ am, const float* __restrict__ att,
        unsigned short* __restrict__ hout) {
    int lane = threadIdx.x & 63;
    int i = blockIdx.x * 4 + (threadIdx.x >> 6);

    int p0 = rowPtr[i], p1 = rowPtr[i + 1];
    float a0 = 0.f, a1 = 0.f, a2 = 0.f, a3 = 0.f;
    int off4 = lane * 4;
    int p = p0;
    for (; p + 7 < p1; p += 8) {
        int j[8];
#pragma unroll
        for (int q = 0; q < 8; ++q) j[q] = (int)colIdx[p + q];
        unsigned w[8];
#pragma unroll
        for (int q = 0; q < 8; ++q) w[q] = *(const unsigned*)(Hq + (size_t)j[q] * 256 + off4);
#pragma unroll
        for (int q = 0; q < 8; ++q) {
            f32x2 d0 = __builtin_amdgcn_cvt_pk_f32_fp8((int)w[q], false);
            f32x2 d1 = __builtin_amdgcn_cvt_pk_f32_fp8((int)w[q], true);
            a0 += d0.x; a1 += d0.y; a2 += d1.x; a3 += d1.y;
        }
    }
    for (; p < p1; ++p) {
        int j = (int)colIdx[p];
        unsigned w = *(const unsigned*)(Hq + (size_t)j * 256 + off4);
        f32x2 d0 = __builtin_amdgcn_cvt_pk_f32_fp8((int)w, false);
        f32x2 d1 = __builtin_amdgcn_cvt_pk_f32_fp8((int)w, true);
        a0 += d0.x; a1 += d0.y; a2 += d1.x; a3 += d1.y;
    }

    uint2 sv = *(const uint2*)(Hs + (size_t)i * 256 + off4);   // 4 bf16 self vals
    float s0 = bflo(sv.x), s1 = bfhi(sv.x), s2 = bflo(sv.y), s3 = bfhi(sv.y);
    float di = dinv[i];
    float l0 = di * (s0 + a0), l1 = di * (s1 + a1);
    float l2 = di * (s2 + a2), l3 = di * (s3 + a3);

    float ol0 = fmaxf(l0, 0.f), ol1 = fmaxf(l1, 0.f);
    float ol2 = fmaxf(l2, 0.f), ol3 = fmaxf(l3, 0.f);
    float oh0 = fmaxf(s0 - l0, 0.f), oh1 = fmaxf(s1 - l1, 0.f);
    float oh2 = fmaxf(s2 - l2, 0.f), oh3 = fmaxf(s3 - l3, 0.f);

    int c0 = ((lane >> 4) << 6) + (lane & 15);   // true feat of q=0

    float om0 = 0.f, om1 = 0.f, om2 = 0.f, om3 = 0.f;
    float prA, prM = 0.f;
    if (lane < 32) {
        uint2 hv = *(const uint2*)(HmP + (size_t)i * 128 + off4);
        om0 = fmaxf(bflo(hv.x), 0.f); om1 = fmaxf(bfhi(hv.x), 0.f);
        om2 = fmaxf(bflo(hv.y), 0.f); om3 = fmaxf(bfhi(hv.y), 0.f);
        prA = ol0 * al[c0] + ol1 * al[c0 + 16] + ol2 * al[c0 + 32] + ol3 * al[c0 + 48];
        prM = om0 * am[c0] + om1 * am[c0 + 16] + om2 * am[c0 + 32] + om3 * am[c0 + 48];
    } else {
        int ch = c0 - 128;
        prA = oh0 * ah[ch] + oh1 * ah[ch + 16] + oh2 * ah[ch + 32] + oh3 * ah[ch + 48];
    }

#pragma unroll
    for (int d = 1; d < 32; d <<= 1) prA += __shfl_xor(prA, d);
#pragma unroll
    for (int d = 1; d < 32; d <<= 1) prM += __shfl_xor(prM, d);
    float g0 = __shfl(prA, 0);
    float g1 = __shfl(prA, 32);
    float g2 = __shfl(prM, 0);

    float sg0 = sigmoidf_(g0), sg1 = sigmoidf_(g1), sg2 = sigmoidf_(g2);
    const float inv3 = (1.0f / 3.0f);
    float e0 = (sg0 * att[0] + sg1 * att[3] + sg2 * att[6]) * inv3;
    float e1 = (sg0 * att[1] + sg1 * att[4] + sg2 * att[7]) * inv3;
    float e2 = (sg0 * att[2] + sg1 * att[5] + sg2 * att[8]) * inv3;
    float mx = fmaxf(e0, fmaxf(e1, e2));
    float x0 = expf(e0 - mx), x1 = expf(e1 - mx), x2 = expf(e2 - mx);
    float inv = 1.0f / (x0 + x1 + x2);
    float c0f = 3.0f * inv * x0, c1f = 3.0f * inv * x1, c2f = 3.0f * inv * x2;

    int src = lane | 32;
    float th0 = __shfl(oh0, src), th1 = __shfl(oh1, src);
    float th2 = __shfl(oh2, src), th3 = __shfl(oh3, src);

    if (lane < 32) {
        // hbuf permuted: pos p = lane*4+q -> true feat c_q (matches W1t k-perm)
        ushort4v o;
        o[0] = f2bf(c0f * ol0 + c1f * th0 + c2f * om0);
        o[1] = f2bf(c0f * ol1 + c1f * th1 + c2f * om1);
        o[2] = f2bf(c0f * ol2 + c1f * th2 + c2f * om2);
        o[3] = f2bf(c0f * ol3 + c1f * th3 + c2f * om3);
        *(ushort4v*)&hout[(size_t)i * 128 + off4] = o;
    }
}

// ---------------- layer 1: wave-per-node aggregate + ACM epilogue ----------------
// H1g[i][c] bf16: c<40 hl, c>=40 hh (80 cols). H1m: hm (40). lanes 0..39 active.

__global__ __launch_bounds__(256) void k_layer1(
        const unsigned short* __restrict__ H1g, const unsigned short* __restrict__ H1m,
        const int* __restrict__ rowPtr, const unsigned short* __restrict__ colIdx,
        const float* __restrict__ dinv,
        const float* __restrict__ al, const float* __restrict__ ah,
        const float* __restrict__ am, const float* __restrict__ att,
        float* __restrict__ out) {
    int lane = threadIdx.x & 63;
    int i = blockIdx.x * 4 + (threadIdx.x >> 6);

    int p0 = rowPtr[i], p1 = rowPtr[i + 1];
    float a0 = 0.f, a1 = 0.f;
    int off = lane * 2;
    bool active = lane < 40;
    int p = p0;
    if (active) {
        for (; p + 7 < p1; p += 8) {
            int j[8];
#pragma unroll
            for (int q = 0; q < 8; ++q) j[q] = (int)colIdx[p + q];
            unsigned v[8];
#pragma unroll
            for (int q = 0; q < 8; ++q) v[q] = *(const unsigned*)(H1g + (size_t)j[q] * 80 + off);
#pragma unroll
            for (int q = 0; q < 8; ++q) { a0 += bflo(v[q]); a1 += bfhi(v[q]); }
        }
        for (; p < p1; ++p) {
            int j = (int)colIdx[p];
            unsigned v = *(const unsigned*)(H1g + (size_t)j * 80 + off);
            a0 += bflo(v); a1 += bfhi(v);
        }
    }

    float s0 = 0.f, s1 = 0.f;
    if (active) {
        unsigned sv = *(const unsigned*)(H1g + (size_t)i * 80 + off);
        s0 = bflo(sv); s1 = bfhi(sv);
    }
    float di = dinv[i];
    float l0 = di * (s0 + a0), l1 = di * (s1 + a1);

    float ol0 = fmaxf(l0, 0.f), ol1 = fmaxf(l1, 0.f);
    float oh0 = fmaxf(s0 - l0, 0.f), oh1 = fmaxf(s1 - l1, 0.f);

    float om0 = 0.f, om1 = 0.f;
    float r0 = 0.f, r1 = 0.f, r2 = 0.f;
    if (lane < 20) {
        unsigned hv = *(const unsigned*)(H1m + (size_t)i * 40 + off);
        om0 = fmaxf(bflo(hv), 0.f); om1 = fmaxf(bfhi(hv), 0.f);
        float2 alv = *(const float2*)(al + off);
        float2 amv = *(const float2*)(am + off);
        r0 = ol0 * alv.x + ol1 * alv.y;
        r2 = om0 * amv.x + om1 * amv.y;
    } else if (lane < 40) {
        float2 ahv = *(const float2*)(ah + (off - 40));
        r1 = oh0 * ahv.x + oh1 * ahv.y;
    }

#pragma unroll
    for (int d = 1; d < 64; d <<= 1) r0 += __shfl_xor(r0, d);
#pragma unroll
    for (int d = 1; d < 64; d <<= 1) r1 += __shfl_xor(r1, d);
#pragma unroll
    for (int d = 1; d < 64; d <<= 1) r2 += __shfl_xor(r2, d);

    float sg0 = sigmoidf_(r0), sg1 = sigmoidf_(r1), sg2 = sigmoidf_(r2);
    const float inv3 = (1.0f / 3.0f);
    float e0 = (sg0 * att[0] + sg1 * att[3] + sg2 * att[6]) * inv3;
    float e1 = (sg0 * att[1] + sg1 * att[4] + sg2 * att[7]) * inv3;
    float e2 = (sg0 * att[2] + sg1 * att[5] + sg2 * att[8]) * inv3;
    float mx = fmaxf(e0, fmaxf(e1, e2));
    float x0 = expf(e0 - mx), x1 = expf(e1 - mx), x2 = expf(e2 - mx);
    float inv = 1.0f / (x0 + x1 + x2);
    float c0 = 3.0f * inv * x0, c1 = 3.0f * inv * x1, c2 = 3.0f * inv * x2;

    int src = (lane + 20) & 63;
    float th0 = __shfl(oh0, src), th1 = __shfl(oh1, src);

    if (lane < 20) {
        float2 o;
        o.x = c0 * ol0 + c1 * th0 + c2 * om0;
        o.y = c0 * ol1 + c1 * th1 + c2 * om1;
        *(float2*)&out[(size_t)i * 40 + off] = o;
    }
}

// ---------------- launch ----------------

extern "C" void kernel_launch(void* const* d_in, const int* in_sizes, int n_in,
                              void* d_out, int out_size, void* d_ws, size_t ws_size,
                              hipStream_t stream) {
    const float* x    = (const float*)d_in[0];
    const int*   ei   = (const int*)d_in[1];
    const float* Wl0  = (const float*)d_in[2];
    const float* Wh0  = (const float*)d_in[3];
    const float* Wm0  = (const float*)d_in[4];
    const float* al0  = (const float*)d_in[5];
    const float* ah0  = (const float*)d_in[6];
    const float* am0  = (const float*)d_in[7];
    const float* att0 = (const float*)d_in[8];
    const float* Wl1  = (const float*)d_in[9];
    const float* Wh1  = (const float*)d_in[10];
    const float* Wm1  = (const float*)d_in[11];
    const float* al1  = (const float*)d_in[12];
    const float* ah1  = (const float*)d_in[13];
    const float* am1  = (const float*)d_in[14];
    const float* att1 = (const float*)d_in[15];
    float* out = (float*)d_out;

    char* ws = (char*)d_ws;
    size_t off = 0;
    auto alloc = [&](size_t bytes) -> char* {
        char* p = ws + off;
        off += (bytes + 255) & ~(size_t)255;
        return p;
    };
    int*   deg    = (int*)  alloc((size_t)N_NODES * 4);
    int*   rowPtr = (int*)  alloc((size_t)(N_NODES + 1) * 4);
    int*   blkTot = (int*)  alloc(256 * 4);
    unsigned short* rank   = (unsigned short*)alloc((size_t)N_EDGES * 2);
    unsigned*       rc     = (unsigned*)      alloc((size_t)N_EDGES * 4);
    unsigned short* colIdx = (unsigned short*)alloc((size_t)N_EDGES * 2);
    float* dinv   = (float*)alloc((size_t)N_NODES * 4);
    unsigned short* W0t  = (unsigned short*)alloc((size_t)W0N * IN_F * 2);
    unsigned short* W1t  = (unsigned short*)alloc((size_t)W1N * HID_F * 2);
    unsigned short* xb   = (unsigned short*)alloc((size_t)N_NODES * IN_F * 2);
    unsigned short* Hs   = (unsigned short*)alloc((size_t)N_NODES * 256 * 2);
    unsigned char*  Hq   = (unsigned char*) alloc((size_t)N_NODES * 256);
    unsigned short* HmP  = (unsigned short*)alloc((size_t)N_NODES * 128 * 2);
    unsigned short* H1g  = (unsigned short*)alloc((size_t)N_NODES * 80 * 2);
    unsigned short* H1m  = (unsigned short*)alloc((size_t)N_NODES * 40 * 2);
    unsigned short* hbuf = (unsigned short*)alloc((size_t)N_NODES * HID_F * 2);

    // 1. zero deg
    hipMemsetAsync(deg, 0, (size_t)N_NODES * 4, stream);
    // 2. fused prep (x->bf16, W packs, degree count + rank + rc)
    k_prep<<<PREPB, 256, 0, stream>>>(x, xb, Wl0, Wh0, Wm0, W0t,
                                      Wl1, Wh1, Wm1, W1t, ei, deg, rank, rc);
    // 3-5. multi-block scan chain (rowPtr + dinv)
    k_scan1<<<NB, 256, 0, stream>>>(deg, rowPtr, blkTot, dinv);
    k_scan2<<<1, 256, 0, stream>>>(blkTot);
    k_scan3<<<NB, 256, 0, stream>>>(deg, blkTot, rowPtr);
    // 6. GEMM0 (layer-0 epilogue: Hs/Hq/HmP) with fused atomic-free CSR fill
    {
        dim3 grid(3 + 8, (N_NODES + 127) / 128);
        k_gemm_fill<1><<<grid, 256, 0, stream>>>(xb, W0t,
                                                 nullptr, 0, nullptr, 0, 0,
                                                 Hs, Hq, HmP,
                                                 N_NODES, W0N, IN_F, 3,
                                                 rc, rank, rowPtr, colIdx);
    }
    // 7. layer-0 aggregate + epilogue
    k_layer0<<<N_NODES / 4, 256, 0, stream>>>(Hs, Hq, HmP, rowPtr, colIdx, dinv,
                                              al0, ah0, am0, att0, hbuf);
    // 8. GEMM1 (plain epilogue -> H1g/H1m)
    {
        dim3 grid(1, (N_NODES + 127) / 128);
        k_gemm_fill<0><<<grid, 256, 0, stream>>>(hbuf, W1t,
                                                 H1g, 80, H1m, 40, 80,
                                                 nullptr, nullptr, nullptr,
                                                 N_NODES, W1N, HID_F, 1,
                                                 nullptr, nullptr, nullptr, nullptr);
    }
    // 9. layer-1 aggregate + epilogue
    k_layer1<<<N_NODES / 4, 256, 0, stream>>>(H1g, H1m, rowPtr, colIdx, dinv,
                                              al1, ah1, am1, att1, out);
}

// Round 8
// 212.804 us; speedup vs baseline: 1.4042x; 1.0034x over previous
//
#include <hip/hip_runtime.h>
#include <math.h>

#define N_NODES 50000
#define N_EDGES 800000
#define IN_F    256
#define HID_F   128
#define OUT_F   40
#define W0N     (3*HID_F)   // 384
#define W1N     (3*OUT_F)   // 120
#define NB      ((N_NODES + 255) / 256)   // 196

// k_prep block ranges
#define XB   ((N_NODES * IN_F) / (256 * 16))   // 3125: x convert, 16 floats/thread
#define P0B  ((IN_F * W0N) / 256)              // 384
#define P1B  ((HID_F * W1N) / 256)             // 60
#define CB0  (XB + P0B + P1B)                  // 3569
#define CEB  (((N_EDGES / 4) + 255) / 256)     // 782: count, 4 edges/thread
#define PREPB (CB0 + CEB)                      // 4351

typedef __attribute__((ext_vector_type(8))) unsigned short ushort8;
typedef __attribute__((ext_vector_type(4))) unsigned short ushort4v;
typedef __attribute__((ext_vector_type(8))) __bf16 bf16x8;
typedef __attribute__((ext_vector_type(4))) float f32x4;
typedef __attribute__((ext_vector_type(2))) float f32x2;

static __device__ __forceinline__ float sigmoidf_(float x) {
    return 1.0f / (1.0f + expf(-x));
}

static __device__ __forceinline__ unsigned short f2bf(float f) {
    unsigned u = __float_as_uint(f);
    u += 0x7FFFu + ((u >> 16) & 1u);
    return (unsigned short)(u >> 16);
}

static __device__ __forceinline__ float bflo(unsigned u) { return __uint_as_float(u << 16); }
static __device__ __forceinline__ float bfhi(unsigned u) { return __uint_as_float(u & 0xffff0000u); }

// ------- fused prep: x->bf16 | pack W0^T | pack W1^T(k-perm) | count+rank+rc -------

__global__ __launch_bounds__(256) void k_prep(
        const float* __restrict__ x, unsigned short* __restrict__ xb,
        const float* __restrict__ Wl0, const float* __restrict__ Wh0,
        const float* __restrict__ Wm0, unsigned short* __restrict__ W0t,
        const float* __restrict__ Wl1, const float* __restrict__ Wh1,
        const float* __restrict__ Wm1, unsigned short* __restrict__ W1t,
        const int* __restrict__ ei, int* __restrict__ deg,
        unsigned short* __restrict__ rank, unsigned* __restrict__ rc) {
    int b = blockIdx.x, t = threadIdx.x;
    if (b < XB) {
        // 16 floats/thread: 4 independent float4 loads in flight
        size_t idx = (size_t)b * 4096 + t * 16;
        float4 f0 = *(const float4*)(x + idx);
        float4 f1 = *(const float4*)(x + idx + 4);
        float4 f2 = *(const float4*)(x + idx + 8);
        float4 f3 = *(const float4*)(x + idx + 12);
        ushort8 u0, u1;
        u0[0]=f2bf(f0.x); u0[1]=f2bf(f0.y); u0[2]=f2bf(f0.z); u0[3]=f2bf(f0.w);
        u0[4]=f2bf(f1.x); u0[5]=f2bf(f1.y); u0[6]=f2bf(f1.z); u0[7]=f2bf(f1.w);
        u1[0]=f2bf(f2.x); u1[1]=f2bf(f2.y); u1[2]=f2bf(f2.z); u1[3]=f2bf(f2.w);
        u1[4]=f2bf(f3.x); u1[5]=f2bf(f3.y); u1[6]=f2bf(f3.z); u1[7]=f2bf(f3.w);
        *(ushort8*)(xb + idx)     = u0;
        *(ushort8*)(xb + idx + 8) = u1;
    } else if (b < XB + P0B) {
        int i = (b - XB) * 256 + t;
        int n = i / IN_F, k = i % IN_F;
        float v;
        if (n < HID_F)            v = Wl0[k * HID_F + n];
        else if (n < 2 * HID_F)   v = Wh0[k * HID_F + (n - HID_F)];
        else                      v = Wm0[k * HID_F + (n - 2 * HID_F)];
        W0t[i] = f2bf(v);
    } else if (b < CB0) {
        int i = (b - XB - P0B) * 256 + t;
        int n = i / HID_F, kp = i % HID_F;
        // k-dim permuted to match hbuf's permuted layout: feat = g*64 + q*16 + c
        int k = ((kp >> 6) << 6) + ((kp & 3) << 4) + ((kp >> 2) & 15);
        float v;
        if (n < OUT_F)            v = Wl1[k * OUT_F + n];
        else if (n < 2 * OUT_F)   v = Wh1[k * OUT_F + (n - OUT_F)];
        else                      v = Wm1[k * OUT_F + (n - 2 * OUT_F)];
        W1t[i] = f2bf(v);
    } else {
        // 4 edges/thread: 4 independent atomics in flight
        int e4 = (b - CB0) * 256 + t;
        if (e4 < N_EDGES / 4) {
            int e = e4 * 4;
            int4 rv = *(const int4*)(ei + e);
            int4 cv = *(const int4*)(ei + N_EDGES + e);
            int o0 = atomicAdd(&deg[rv.x], 1);
            int o1 = atomicAdd(&deg[rv.y], 1);
            int o2 = atomicAdd(&deg[rv.z], 1);
            int o3 = atomicAdd(&deg[rv.w], 1);
            ushort4v rk;
            rk[0] = (unsigned short)o0; rk[1] = (unsigned short)o1;
            rk[2] = (unsigned short)o2; rk[3] = (unsigned short)o3;
            *(ushort4v*)(rank + e) = rk;
            uint4 rcv;
            rcv.x = ((unsigned)rv.x << 16) | (unsigned)cv.x;
            rcv.y = ((unsigned)rv.y << 16) | (unsigned)cv.y;
            rcv.z = ((unsigned)rv.z << 16) | (unsigned)cv.z;
            rcv.w = ((unsigned)rv.w << 16) | (unsigned)cv.w;
            *(uint4*)(rc + e) = rcv;
        }
    }
}

// ---------------- CSR scan (multi-block, 3 kernels) ----------------

__global__ void k_scan1(const int* __restrict__ deg, int* __restrict__ rowPtr,
                        int* __restrict__ blkTot, float* __restrict__ dinv) {
    __shared__ int s[256];
    int t = threadIdx.x;
    int gid = blockIdx.x * 256 + t;
    int v = (gid < N_NODES) ? deg[gid] : 0;
    if (gid < N_NODES) dinv[gid] = 1.0f / (1.0f + (float)v);
    s[t] = v; __syncthreads();
    for (int d = 1; d < 256; d <<= 1) {
        int x = (t >= d) ? s[t - d] : 0;
        __syncthreads();
        s[t] += x;
        __syncthreads();
    }
    if (gid < N_NODES) rowPtr[gid] = s[t];
    if (t == 255) blkTot[blockIdx.x] = s[255];
}

__global__ void k_scan2(int* __restrict__ blk) {
    __shared__ int s[256];
    int t = threadIdx.x;
    int v = (t < NB) ? blk[t] : 0;
    s[t] = v; __syncthreads();
    for (int d = 1; d < 256; d <<= 1) {
        int x = (t >= d) ? s[t - d] : 0;
        __syncthreads();
        s[t] += x;
        __syncthreads();
    }
    if (t < NB) blk[t] = s[t] - v;
}

__global__ void k_scan3(const int* __restrict__ deg, const int* __restrict__ blkOff,
                        int* __restrict__ rowPtr) {
    int t = threadIdx.x;
    int gid = blockIdx.x * 256 + t;
    if (gid < N_NODES) rowPtr[gid] += blkOff[blockIdx.x] - deg[gid];
    if (gid == 0) rowPtr[N_NODES] = N_EDGES;
}

// ---------------- bf16 MFMA GEMM + optional fused CSR-fill ----------------
// tile 128x128, BK=32, 4 waves (2x2).
// EPI=0: plain bf16 split write: cols [0,nsplit)->C0(ld0), rest->C1(ld1).
// EPI=1: layer-0 write: Hs (bf16 perm), Hq (fp8 perm), HmP (bf16 perm).
//   permuted pos within 64-col group: pos = col*4 + n  <->  feat = n*16 + col

#define BKP 40   // 32 + 8 pad

template<int EPI>
__global__ __launch_bounds__(256) void k_gemm_fill(
        const unsigned short* __restrict__ A, const unsigned short* __restrict__ Bt,
        unsigned short* __restrict__ C0, int ld0,
        unsigned short* __restrict__ C1, int ld1, int nsplit,
        unsigned short* __restrict__ Hs, unsigned char* __restrict__ Hq,
        unsigned short* __restrict__ HmP,
        int M, int N, int K, int nxt,
        const unsigned* __restrict__ rc, const unsigned short* __restrict__ rank,
        const int* __restrict__ rowPtr, unsigned short* __restrict__ colIdx) {
    __shared__ unsigned short As[128 * BKP];
    __shared__ unsigned short Bs[128 * BKP];
    int tid  = threadIdx.x;

    if ((int)blockIdx.x >= nxt) {
        int fid = (blockIdx.x - nxt) * gridDim.y + blockIdx.y;
        int e = fid * 256 + tid;
        if (e < N_EDGES) {
            unsigned x = rc[e];
            int r = (int)(x >> 16);
            int pos = rowPtr[r] + (int)rank[e];
            colIdx[pos] = (unsigned short)(x & 0xffffu);
        }
        return;
    }

    int lane = tid & 63, wid = tid >> 6;
    int wr = wid >> 1, wc = wid & 1;
    int bm = blockIdx.y * 128, bn = blockIdx.x * 128;

    int srow = tid >> 1;
    int scol = (tid & 1) * 16;

    int garow = min(bm + srow, M - 1);
    int gbrow = min(bn + srow, N - 1);

    f32x4 acc[4][4];
#pragma unroll
    for (int m = 0; m < 4; ++m)
#pragma unroll
        for (int n = 0; n < 4; ++n)
            acc[m][n] = (f32x4)(0.0f);

    int kg = (lane >> 4) * 8;
    int rA = wr * 64 + (lane & 15);
    int rB = wc * 64 + (lane & 15);

    for (int k0 = 0; k0 < K; k0 += 32) {
        {
            const unsigned short* src = A + (size_t)garow * K + k0 + scol;
            *(ushort8*)&As[srow * BKP + scol]     = *(const ushort8*)(src);
            *(ushort8*)&As[srow * BKP + scol + 8] = *(const ushort8*)(src + 8);
        }
        {
            const unsigned short* src = Bt + (size_t)gbrow * K + k0 + scol;
            *(ushort8*)&Bs[srow * BKP + scol]     = *(const ushort8*)(src);
            *(ushort8*)&Bs[srow * BKP + scol + 8] = *(const ushort8*)(src + 8);
        }
        __syncthreads();

        bf16x8 a[4], b[4];
#pragma unroll
        for (int m = 0; m < 4; ++m)
            a[m] = __builtin_bit_cast(bf16x8, *(const ushort8*)&As[(rA + m * 16) * BKP + kg]);
#pragma unroll
        for (int n = 0; n < 4; ++n)
            b[n] = __builtin_bit_cast(bf16x8, *(const ushort8*)&Bs[(rB + n * 16) * BKP + kg]);
#pragma unroll
        for (int m = 0; m < 4; ++m)
#pragma unroll
            for (int n = 0; n < 4; ++n)
                acc[m][n] = __builtin_amdgcn_mfma_f32_16x16x32_bf16(a[m], b[n], acc[m][n], 0, 0, 0);
        __syncthreads();
    }

    int col  = lane & 15;
    int rsub = (lane >> 4) * 4;

    if (EPI == 0) {
#pragma unroll
        for (int m = 0; m < 4; ++m) {
            int gm0 = bm + wr * 64 + m * 16 + rsub;
#pragma unroll
            for (int n = 0; n < 4; ++n) {
                int gn = bn + wc * 64 + n * 16 + col;
                if (gn >= N) continue;
#pragma unroll
                for (int j = 0; j < 4; ++j) {
                    int gm = gm0 + j;
                    if (gm >= M) continue;
                    unsigned short b = f2bf(acc[m][n][j]);
                    if (gn < nsplit) C0[(size_t)gm * ld0 + gn] = b;
                    else             C1[(size_t)gm * ld1 + (gn - nsplit)] = b;
                }
            }
        }
    } else {
        // permuted writes; this thread covers pos base = bn + wc*64 + col*4
#pragma unroll
        for (int m = 0; m < 4; ++m) {
            int gm0 = bm + wr * 64 + m * 16 + rsub;
#pragma unroll
            for (int j = 0; j < 4; ++j) {
                int gm = gm0 + j;
                if (gm >= M) continue;
                float v0 = acc[m][0][j], v1 = acc[m][1][j];
                float v2 = acc[m][2][j], v3 = acc[m][3][j];
                ushort4v o;
                o[0] = f2bf(v0); o[1] = f2bf(v1); o[2] = f2bf(v2); o[3] = f2bf(v3);
                if (bn < 256) {
                    int pos = bn + wc * 64 + col * 4;
                    *(ushort4v*)&Hs[(size_t)gm * 256 + pos] = o;
                    int pk = 0;
                    pk = __builtin_amdgcn_cvt_pk_fp8_f32(v0, v1, pk, false);
                    pk = __builtin_amdgcn_cvt_pk_fp8_f32(v2, v3, pk, true);
                    *(unsigned*)&Hq[(size_t)gm * 256 + pos] = (unsigned)pk;
                } else {
                    int pos = wc * 64 + col * 4;
                    *(ushort4v*)&HmP[(size_t)gm * 128 + pos] = o;
                }
            }
        }
    }
}

// ---------------- layer 0: wave-per-node, fp8 neighbor gather + ACM epilogue ----------------
// Hq fp8 perm [256 B/row]; Hs bf16 perm [256]; HmP bf16 perm [128].
// lane's 4 true feats: c_q = (lane>>4)*64 + q*16 + (lane&15); lanes<32 = hl, >=32 = hh.

__global__ __launch_bounds__(256) void k_layer0(
        const unsigned short* __restrict__ Hs, const unsigned char* __restrict__ Hq,
        const unsigned short* __restrict__ HmP,
        const int* __restrict__ rowPtr, const unsigned short* __restrict__ colIdx,
        const float* __restrict__ dinv,
        const float* __restrict__ al, const float* __restrict__ ah,
        const float* __restrict__ am, const float* __restrict__ att,
        unsigned short* __restrict__ hout) {
    int lane = threadIdx.x & 63;
    int i = blockIdx.x * 4 + (threadIdx.x >> 6);

    int p0 = rowPtr[i], p1 = rowPtr[i + 1];
    float a0 = 0.f, a1 = 0.f, a2 = 0.f, a3 = 0.f;
    int off4 = lane * 4;
    int p = p0;
    for (; p + 7 < p1; p += 8) {
        int j[8];
#pragma unroll
        for (int q = 0; q < 8; ++q) j[q] = (int)colIdx[p + q];
        unsigned w[8];
#pragma unroll
        for (int q = 0; q < 8; ++q) w[q] = *(const unsigned*)(Hq + (size_t)j[q] * 256 + off4);
#pragma unroll
        for (int q = 0; q < 8; ++q) {
            f32x2 d0 = __builtin_amdgcn_cvt_pk_f32_fp8((int)w[q], false);
            f32x2 d1 = __builtin_amdgcn_cvt_pk_f32_fp8((int)w[q], true);
            a0 += d0.x; a1 += d0.y; a2 += d1.x; a3 += d1.y;
        }
    }
    for (; p < p1; ++p) {
        int j = (int)colIdx[p];
        unsigned w = *(const unsigned*)(Hq + (size_t)j * 256 + off4);
        f32x2 d0 = __builtin_amdgcn_cvt_pk_f32_fp8((int)w, false);
        f32x2 d1 = __builtin_amdgcn_cvt_pk_f32_fp8((int)w, true);
        a0 += d0.x; a1 += d0.y; a2 += d1.x; a3 += d1.y;
    }

    uint2 sv = *(const uint2*)(Hs + (size_t)i * 256 + off4);   // 4 bf16 self vals
    float s0 = bflo(sv.x), s1 = bfhi(sv.x), s2 = bflo(sv.y), s3 = bfhi(sv.y);
    float di = dinv[i];
    float l0 = di * (s0 + a0), l1 = di * (s1 + a1);
    float l2 = di * (s2 + a2), l3 = di * (s3 + a3);

    float ol0 = fmaxf(l0, 0.f), ol1 = fmaxf(l1, 0.f);
    float ol2 = fmaxf(l2, 0.f), ol3 = fmaxf(l3, 0.f);
    float oh0 = fmaxf(s0 - l0, 0.f), oh1 = fmaxf(s1 - l1, 0.f);
    float oh2 = fmaxf(s2 - l2, 0.f), oh3 = fmaxf(s3 - l3, 0.f);

    int c0 = ((lane >> 4) << 6) + (lane & 15);   // true feat of q=0

    float om0 = 0.f, om1 = 0.f, om2 = 0.f, om3 = 0.f;
    float prA, prM = 0.f;
    if (lane < 32) {
        uint2 hv = *(const uint2*)(HmP + (size_t)i * 128 + off4);
        om0 = fmaxf(bflo(hv.x), 0.f); om1 = fmaxf(bfhi(hv.x), 0.f);
        om2 = fmaxf(bflo(hv.y), 0.f); om3 = fmaxf(bfhi(hv.y), 0.f);
        prA = ol0 * al[c0] + ol1 * al[c0 + 16] + ol2 * al[c0 + 32] + ol3 * al[c0 + 48];
        prM = om0 * am[c0] + om1 * am[c0 + 16] + om2 * am[c0 + 32] + om3 * am[c0 + 48];
    } else {
        int ch = c0 - 128;
        prA = oh0 * ah[ch] + oh1 * ah[ch + 16] + oh2 * ah[ch + 32] + oh3 * ah[ch + 48];
    }

#pragma unroll
    for (int d = 1; d < 32; d <<= 1) prA += __shfl_xor(prA, d);
#pragma unroll
    for (int d = 1; d < 32; d <<= 1) prM += __shfl_xor(prM, d);
    float g0 = __shfl(prA, 0);
    float g1 = __shfl(prA, 32);
    float g2 = __shfl(prM, 0);

    float sg0 = sigmoidf_(g0), sg1 = sigmoidf_(g1), sg2 = sigmoidf_(g2);
    const float inv3 = (1.0f / 3.0f);
    float e0 = (sg0 * att[0] + sg1 * att[3] + sg2 * att[6]) * inv3;
    float e1 = (sg0 * att[1] + sg1 * att[4] + sg2 * att[7]) * inv3;
    float e2 = (sg0 * att[2] + sg1 * att[5] + sg2 * att[8]) * inv3;
    float mx = fmaxf(e0, fmaxf(e1, e2));
    float x0 = expf(e0 - mx), x1 = expf(e1 - mx), x2 = expf(e2 - mx);
    float inv = 1.0f / (x0 + x1 + x2);
    float c0f = 3.0f * inv * x0, c1f = 3.0f * inv * x1, c2f = 3.0f * inv * x2;

    int src = lane | 32;
    float th0 = __shfl(oh0, src), th1 = __shfl(oh1, src);
    float th2 = __shfl(oh2, src), th3 = __shfl(oh3, src);

    if (lane < 32) {
        // hbuf permuted: pos p = lane*4+q -> true feat c_q (matches W1t k-perm)
        ushort4v o;
        o[0] = f2bf(c0f * ol0 + c1f * th0 + c2f * om0);
        o[1] = f2bf(c0f * ol1 + c1f * th1 + c2f * om1);
        o[2] = f2bf(c0f * ol2 + c1f * th2 + c2f * om2);
        o[3] = f2bf(c0f * ol3 + c1f * th3 + c2f * om3);
        *(ushort4v*)&hout[(size_t)i * 128 + off4] = o;
    }
}

// ---------------- layer 1: wave-per-node aggregate + ACM epilogue ----------------
// H1g[i][c] bf16: c<40 hl, c>=40 hh (80 cols). H1m: hm (40). lanes 0..39 active.

__global__ __launch_bounds__(256) void k_layer1(
        const unsigned short* __restrict__ H1g, const unsigned short* __restrict__ H1m,
        const int* __restrict__ rowPtr, const unsigned short* __restrict__ colIdx,
        const float* __restrict__ dinv,
        const float* __restrict__ al, const float* __restrict__ ah,
        const float* __restrict__ am, const float* __restrict__ att,
        float* __restrict__ out) {
    int lane = threadIdx.x & 63;
    int i = blockIdx.x * 4 + (threadIdx.x >> 6);

    int p0 = rowPtr[i], p1 = rowPtr[i + 1];
    float a0 = 0.f, a1 = 0.f;
    int off = lane * 2;
    bool active = lane < 40;
    int p = p0;
    if (active) {
        for (; p + 7 < p1; p += 8) {
            int j[8];
#pragma unroll
            for (int q = 0; q < 8; ++q) j[q] = (int)colIdx[p + q];
            unsigned v[8];
#pragma unroll
            for (int q = 0; q < 8; ++q) v[q] = *(const unsigned*)(H1g + (size_t)j[q] * 80 + off);
#pragma unroll
            for (int q = 0; q < 8; ++q) { a0 += bflo(v[q]); a1 += bfhi(v[q]); }
        }
        for (; p < p1; ++p) {
            int j = (int)colIdx[p];
            unsigned v = *(const unsigned*)(H1g + (size_t)j * 80 + off);
            a0 += bflo(v); a1 += bfhi(v);
        }
    }

    float s0 = 0.f, s1 = 0.f;
    if (active) {
        unsigned sv = *(const unsigned*)(H1g + (size_t)i * 80 + off);
        s0 = bflo(sv); s1 = bfhi(sv);
    }
    float di = dinv[i];
    float l0 = di * (s0 + a0), l1 = di * (s1 + a1);

    float ol0 = fmaxf(l0, 0.f), ol1 = fmaxf(l1, 0.f);
    float oh0 = fmaxf(s0 - l0, 0.f), oh1 = fmaxf(s1 - l1, 0.f);

    float om0 = 0.f, om1 = 0.f;
    float r0 = 0.f, r1 = 0.f, r2 = 0.f;
    if (lane < 20) {
        unsigned hv = *(const unsigned*)(H1m + (size_t)i * 40 + off);
        om0 = fmaxf(bflo(hv), 0.f); om1 = fmaxf(bfhi(hv), 0.f);
        float2 alv = *(const float2*)(al + off);
        float2 amv = *(const float2*)(am + off);
        r0 = ol0 * alv.x + ol1 * alv.y;
        r2 = om0 * amv.x + om1 * amv.y;
    } else if (lane < 40) {
        float2 ahv = *(const float2*)(ah + (off - 40));
        r1 = oh0 * ahv.x + oh1 * ahv.y;
    }

#pragma unroll
    for (int d = 1; d < 64; d <<= 1) r0 += __shfl_xor(r0, d);
#pragma unroll
    for (int d = 1; d < 64; d <<= 1) r1 += __shfl_xor(r1, d);
#pragma unroll
    for (int d = 1; d < 64; d <<= 1) r2 += __shfl_xor(r2, d);

    float sg0 = sigmoidf_(r0), sg1 = sigmoidf_(r1), sg2 = sigmoidf_(r2);
    const float inv3 = (1.0f / 3.0f);
    float e0 = (sg0 * att[0] + sg1 * att[3] + sg2 * att[6]) * inv3;
    float e1 = (sg0 * att[1] + sg1 * att[4] + sg2 * att[7]) * inv3;
    float e2 = (sg0 * att[2] + sg1 * att[5] + sg2 * att[8]) * inv3;
    float mx = fmaxf(e0, fmaxf(e1, e2));
    float x0 = expf(e0 - mx), x1 = expf(e1 - mx), x2 = expf(e2 - mx);
    float inv = 1.0f / (x0 + x1 + x2);
    float c0 = 3.0f * inv * x0, c1 = 3.0f * inv * x1, c2 = 3.0f * inv * x2;

    int src = (lane + 20) & 63;
    float th0 = __shfl(oh0, src), th1 = __shfl(oh1, src);

    if (lane < 20) {
        float2 o;
        o.x = c0 * ol0 + c1 * th0 + c2 * om0;
        o.y = c0 * ol1 + c1 * th1 + c2 * om1;
        *(float2*)&out[(size_t)i * 40 + off] = o;
    }
}

// ---------------- launch ----------------

extern "C" void kernel_launch(void* const* d_in, const int* in_sizes, int n_in,
                              void* d_out, int out_size, void* d_ws, size_t ws_size,
                              hipStream_t stream) {
    const float* x    = (const float*)d_in[0];
    const int*   ei   = (const int*)d_in[1];
    const float* Wl0  = (const float*)d_in[2];
    const float* Wh0  = (const float*)d_in[3];
    const float* Wm0  = (const float*)d_in[4];
    const float* al0  = (const float*)d_in[5];
    const float* ah0  = (const float*)d_in[6];
    const float* am0  = (const float*)d_in[7];
    const float* att0 = (const float*)d_in[8];
    const float* Wl1  = (const float*)d_in[9];
    const float* Wh1  = (const float*)d_in[10];
    const float* Wm1  = (const float*)d_in[11];
    const float* al1  = (const float*)d_in[12];
    const float* ah1  = (const float*)d_in[13];
    const float* am1  = (const float*)d_in[14];
    const float* att1 = (const float*)d_in[15];
    float* out = (float*)d_out;

    char* ws = (char*)d_ws;
    size_t off = 0;
    auto alloc = [&](size_t bytes) -> char* {
        char* p = ws + off;
        off += (bytes + 255) & ~(size_t)255;
        return p;
    };
    int*   deg    = (int*)  alloc((size_t)N_NODES * 4);
    int*   rowPtr = (int*)  alloc((size_t)(N_NODES + 1) * 4);
    int*   blkTot = (int*)  alloc(256 * 4);
    unsigned short* rank   = (unsigned short*)alloc((size_t)N_EDGES * 2);
    unsigned*       rc     = (unsigned*)      alloc((size_t)N_EDGES * 4);
    unsigned short* colIdx = (unsigned short*)alloc((size_t)N_EDGES * 2);
    float* dinv   = (float*)alloc((size_t)N_NODES * 4);
    unsigned short* W0t  = (unsigned short*)alloc((size_t)W0N * IN_F * 2);
    unsigned short* W1t  = (unsigned short*)alloc((size_t)W1N * HID_F * 2);
    unsigned short* xb   = (unsigned short*)alloc((size_t)N_NODES * IN_F * 2);
    unsigned short* Hs   = (unsigned short*)alloc((size_t)N_NODES * 256 * 2);
    unsigned char*  Hq   = (unsigned char*) alloc((size_t)N_NODES * 256);
    unsigned short* HmP  = (unsigned short*)alloc((size_t)N_NODES * 128 * 2);
    unsigned short* H1g  = (unsigned short*)alloc((size_t)N_NODES * 80 * 2);
    unsigned short* H1m  = (unsigned short*)alloc((size_t)N_NODES * 40 * 2);
    unsigned short* hbuf = (unsigned short*)alloc((size_t)N_NODES * HID_F * 2);

    // 1. zero deg
    hipMemsetAsync(deg, 0, (size_t)N_NODES * 4, stream);
    // 2. fused prep (x->bf16, W packs, degree count + rank + rc)
    k_prep<<<PREPB, 256, 0, stream>>>(x, xb, Wl0, Wh0, Wm0, W0t,
                                      Wl1, Wh1, Wm1, W1t, ei, deg, rank, rc);
    // 3-5. multi-block scan chain (rowPtr + dinv)
    k_scan1<<<NB, 256, 0, stream>>>(deg, rowPtr, blkTot, dinv);
    k_scan2<<<1, 256, 0, stream>>>(blkTot);
    k_scan3<<<NB, 256, 0, stream>>>(deg, blkTot, rowPtr);
    // 6. GEMM0 (layer-0 epilogue: Hs/Hq/HmP) with fused atomic-free CSR fill
    {
        dim3 grid(3 + 8, (N_NODES + 127) / 128);
        k_gemm_fill<1><<<grid, 256, 0, stream>>>(xb, W0t,
                                                 nullptr, 0, nullptr, 0, 0,
                                                 Hs, Hq, HmP,
                                                 N_NODES, W0N, IN_F, 3,
                                                 rc, rank, rowPtr, colIdx);
    }
    // 7. layer-0 aggregate + epilogue
    k_layer0<<<N_NODES / 4, 256, 0, stream>>>(Hs, Hq, HmP, rowPtr, colIdx, dinv,
                                              al0, ah0, am0, att0, hbuf);
    // 8. GEMM1 (plain epilogue -> H1g/H1m)
    {
        dim3 grid(1, (N_NODES + 127) / 128);
        k_gemm_fill<0><<<grid, 256, 0, stream>>>(hbuf, W1t,
                                                 H1g, 80, H1m, 40, 80,
                                                 nullptr, nullptr, nullptr,
                                                 N_NODES, W1N, HID_F, 1,
                                                 nullptr, nullptr, nullptr, nullptr);
    }
    // 9. layer-1 aggregate + epilogue
    k_layer1<<<N_NODES / 4, 256, 0, stream>>>(H1g, H1m, rowPtr, colIdx, dinv,
                                              al1, ah1, am1, att1, out);
}

// Round 9
// 201.797 us; speedup vs baseline: 1.4808x; 1.0545x over previous
//
#include <hip/hip_runtime.h>
#include <math.h>

#define N_NODES 50000
#define N_EDGES 800000
#define IN_F    256
#define HID_F   128
#define OUT_F   40
#define W0N     (3*HID_F)   // 384
#define W1N     (3*OUT_F)   // 120
#define NB      ((N_NODES + 255) / 256)   // 196

#define SEG     128
#define EPB     (N_EDGES / SEG)           // 6250 edges per segment
#define NWORD   (N_NODES / 2)             // 25000 packed words (2 nodes/word)
#define WB      ((NWORD + 255) / 256)     // 98 scanseg blocks

// k_prep block ranges (convert + weight packs only)
#define XB   ((N_NODES * IN_F) / (256 * 16))   // 3125: x convert, 16 floats/thread
#define P0B  ((IN_F * W0N) / 256)              // 384
#define P1B  ((HID_F * W1N) / 256)             // 60
#define PREPB (XB + P0B + P1B)                 // 3569

typedef __attribute__((ext_vector_type(8))) unsigned short ushort8;
typedef __attribute__((ext_vector_type(4))) unsigned short ushort4v;
typedef __attribute__((ext_vector_type(8))) __bf16 bf16x8;
typedef __attribute__((ext_vector_type(4))) float f32x4;
typedef __attribute__((ext_vector_type(2))) float f32x2;

static __device__ __forceinline__ float sigmoidf_(float x) {
    return 1.0f / (1.0f + expf(-x));
}

static __device__ __forceinline__ unsigned short f2bf(float f) {
    unsigned u = __float_as_uint(f);
    u += 0x7FFFu + ((u >> 16) & 1u);
    return (unsigned short)(u >> 16);
}

static __device__ __forceinline__ float bflo(unsigned u) { return __uint_as_float(u << 16); }
static __device__ __forceinline__ float bfhi(unsigned u) { return __uint_as_float(u & 0xffff0000u); }

// ------- segmented LDS histogram: deg counts + local rank + rc, NO global atomics -------

__global__ __launch_bounds__(256) void k_hist(
        const int* __restrict__ ei, unsigned* __restrict__ segHist,
        unsigned short* __restrict__ rank, unsigned* __restrict__ rc) {
    __shared__ unsigned hist[NWORD];   // 100 KB: 2 u16 counters per word
    int t = threadIdx.x, seg = blockIdx.x;
    for (int i = t; i < NWORD; i += 256) hist[i] = 0;
    __syncthreads();
    int base = seg * EPB;
    for (int k = t; k < EPB; k += 256) {
        int e = base + k;
        int r = ei[e];
        int c = ei[N_EDGES + e];
        unsigned old = atomicAdd(&hist[r >> 1], (r & 1) ? 0x10000u : 1u);
        unsigned lr = (r & 1) ? (old >> 16) : (old & 0xffffu);
        rank[e] = (unsigned short)lr;
        rc[e] = ((unsigned)r << 16) | (unsigned)c;
    }
    __syncthreads();
    unsigned* dst = segHist + (size_t)seg * NWORD;
    for (int i = t; i < NWORD; i += 256) dst[i] = hist[i];
}

// ------- scanseg: in-place segHist -> per-segment offsets; local rowPtr + dinv + blkTot -------

__global__ __launch_bounds__(256) void k_scanseg(
        unsigned* __restrict__ segHist, int* __restrict__ rowPtr,
        float* __restrict__ dinv, int* __restrict__ blkTot) {
    __shared__ int s[256];
    int t = threadIdx.x;
    int w = blockIdx.x * 256 + t;    // packed word = nodes 2w, 2w+1
    int cum0 = 0, cum1 = 0;
    if (w < NWORD) {
        for (int sg = 0; sg < SEG; ++sg) {
            size_t idx = (size_t)sg * NWORD + w;
            unsigned h = segHist[idx];
            segHist[idx] = ((unsigned)cum1 << 16) | (unsigned)cum0;  // offset-before
            cum0 += (int)(h & 0xffffu);
            cum1 += (int)(h >> 16);
        }
    }
    int deg0 = cum0, deg1 = cum1;
    int pair = deg0 + deg1;
    s[t] = pair; __syncthreads();
    for (int d = 1; d < 256; d <<= 1) {
        int x = (t >= d) ? s[t - d] : 0;
        __syncthreads();
        s[t] += x;
        __syncthreads();
    }
    int basep = s[t] - pair;   // exclusive prefix within block
    if (w < NWORD) {
        rowPtr[2 * w]     = basep;
        rowPtr[2 * w + 1] = basep + deg0;
        dinv[2 * w]     = 1.0f / (1.0f + (float)deg0);
        dinv[2 * w + 1] = 1.0f / (1.0f + (float)deg1);
    }
    if (t == 255) blkTot[blockIdx.x] = s[255];
}

__global__ void k_scan2(int* __restrict__ blk) {
    __shared__ int s[256];
    int t = threadIdx.x;
    int v = (t < WB) ? blk[t] : 0;
    s[t] = v; __syncthreads();
    for (int d = 1; d < 256; d <<= 1) {
        int x = (t >= d) ? s[t - d] : 0;
        __syncthreads();
        s[t] += x;
        __syncthreads();
    }
    if (t < WB) blk[t] = s[t] - v;
}

__global__ void k_scan3(const int* __restrict__ blkOff, int* __restrict__ rowPtr) {
    int t = threadIdx.x;
    int gid = blockIdx.x * 256 + t;
    if (gid < N_NODES) rowPtr[gid] += blkOff[gid >> 9];   // 512 nodes per scanseg block
    if (gid == 0) rowPtr[N_NODES] = N_EDGES;
}

// ------- fused prep: x->bf16 | pack W0^T | pack W1^T(k-perm) -------

__global__ __launch_bounds__(256) void k_prep(
        const float* __restrict__ x, unsigned short* __restrict__ xb,
        const float* __restrict__ Wl0, const float* __restrict__ Wh0,
        const float* __restrict__ Wm0, unsigned short* __restrict__ W0t,
        const float* __restrict__ Wl1, const float* __restrict__ Wh1,
        const float* __restrict__ Wm1, unsigned short* __restrict__ W1t) {
    int b = blockIdx.x, t = threadIdx.x;
    if (b < XB) {
        size_t idx = (size_t)b * 4096 + t * 16;
        float4 f0 = *(const float4*)(x + idx);
        float4 f1 = *(const float4*)(x + idx + 4);
        float4 f2 = *(const float4*)(x + idx + 8);
        float4 f3 = *(const float4*)(x + idx + 12);
        ushort8 u0, u1;
        u0[0]=f2bf(f0.x); u0[1]=f2bf(f0.y); u0[2]=f2bf(f0.z); u0[3]=f2bf(f0.w);
        u0[4]=f2bf(f1.x); u0[5]=f2bf(f1.y); u0[6]=f2bf(f1.z); u0[7]=f2bf(f1.w);
        u1[0]=f2bf(f2.x); u1[1]=f2bf(f2.y); u1[2]=f2bf(f2.z); u1[3]=f2bf(f2.w);
        u1[4]=f2bf(f3.x); u1[5]=f2bf(f3.y); u1[6]=f2bf(f3.z); u1[7]=f2bf(f3.w);
        *(ushort8*)(xb + idx)     = u0;
        *(ushort8*)(xb + idx + 8) = u1;
    } else if (b < XB + P0B) {
        int i = (b - XB) * 256 + t;
        int n = i / IN_F, k = i % IN_F;
        float v;
        if (n < HID_F)            v = Wl0[k * HID_F + n];
        else if (n < 2 * HID_F)   v = Wh0[k * HID_F + (n - HID_F)];
        else                      v = Wm0[k * HID_F + (n - 2 * HID_F)];
        W0t[i] = f2bf(v);
    } else {
        int i = (b - XB - P0B) * 256 + t;
        int n = i / HID_F, kp = i % HID_F;
        // k-dim permuted to match hbuf's permuted layout: feat = g*64 + q*16 + c
        int k = ((kp >> 6) << 6) + ((kp & 3) << 4) + ((kp >> 2) & 15);
        float v;
        if (n < OUT_F)            v = Wl1[k * OUT_F + n];
        else if (n < 2 * OUT_F)   v = Wh1[k * OUT_F + (n - OUT_F)];
        else                      v = Wm1[k * OUT_F + (n - 2 * OUT_F)];
        W1t[i] = f2bf(v);
    }
}

// ---------------- bf16 MFMA GEMM + optional fused atomic-free CSR-fill ----------------
// tile 128x128, BK=32, 4 waves (2x2).
// EPI=0: plain bf16 split write: cols [0,nsplit)->C0(ld0), rest->C1(ld1).
// EPI=1: layer-0 write: Hs (bf16 perm), Hq (fp8 perm), HmP (bf16 perm).
//   permuted pos within 64-col group: pos = col*4 + n  <->  feat = n*16 + col

#define BKP 40   // 32 + 8 pad

template<int EPI>
__global__ __launch_bounds__(256) void k_gemm_fill(
        const unsigned short* __restrict__ A, const unsigned short* __restrict__ Bt,
        unsigned short* __restrict__ C0, int ld0,
        unsigned short* __restrict__ C1, int ld1, int nsplit,
        unsigned short* __restrict__ Hs, unsigned char* __restrict__ Hq,
        unsigned short* __restrict__ HmP,
        int M, int N, int K, int nxt,
        const unsigned* __restrict__ rc, const unsigned short* __restrict__ rank,
        const int* __restrict__ rowPtr, const unsigned short* __restrict__ segOff,
        unsigned short* __restrict__ colIdx) {
    __shared__ unsigned short As[128 * BKP];
    __shared__ unsigned short Bs[128 * BKP];
    int tid  = threadIdx.x;

    if ((int)blockIdx.x >= nxt) {
        int fid = (blockIdx.x - nxt) * gridDim.y + blockIdx.y;
        int e = fid * 256 + tid;
        if (e < N_EDGES) {
            unsigned x = rc[e];
            int r = (int)(x >> 16);
            int seg = e / EPB;
            int pos = rowPtr[r] + (int)segOff[(size_t)seg * N_NODES + r] + (int)rank[e];
            colIdx[pos] = (unsigned short)(x & 0xffffu);
        }
        return;
    }

    int lane = tid & 63, wid = tid >> 6;
    int wr = wid >> 1, wc = wid & 1;
    int bm = blockIdx.y * 128, bn = blockIdx.x * 128;

    int srow = tid >> 1;
    int scol = (tid & 1) * 16;

    int garow = min(bm + srow, M - 1);
    int gbrow = min(bn + srow, N - 1);

    f32x4 acc[4][4];
#pragma unroll
    for (int m = 0; m < 4; ++m)
#pragma unroll
        for (int n = 0; n < 4; ++n)
            acc[m][n] = (f32x4)(0.0f);

    int kg = (lane >> 4) * 8;
    int rA = wr * 64 + (lane & 15);
    int rB = wc * 64 + (lane & 15);

    for (int k0 = 0; k0 < K; k0 += 32) {
        {
            const unsigned short* src = A + (size_t)garow * K + k0 + scol;
            *(ushort8*)&As[srow * BKP + scol]     = *(const ushort8*)(src);
            *(ushort8*)&As[srow * BKP + scol + 8] = *(const ushort8*)(src + 8);
        }
        {
            const unsigned short* src = Bt + (size_t)gbrow * K + k0 + scol;
            *(ushort8*)&Bs[srow * BKP + scol]     = *(const ushort8*)(src);
            *(ushort8*)&Bs[srow * BKP + scol + 8] = *(const ushort8*)(src + 8);
        }
        __syncthreads();

        bf16x8 a[4], b[4];
#pragma unroll
        for (int m = 0; m < 4; ++m)
            a[m] = __builtin_bit_cast(bf16x8, *(const ushort8*)&As[(rA + m * 16) * BKP + kg]);
#pragma unroll
        for (int n = 0; n < 4; ++n)
            b[n] = __builtin_bit_cast(bf16x8, *(const ushort8*)&Bs[(rB + n * 16) * BKP + kg]);
#pragma unroll
        for (int m = 0; m < 4; ++m)
#pragma unroll
            for (int n = 0; n < 4; ++n)
                acc[m][n] = __builtin_amdgcn_mfma_f32_16x16x32_bf16(a[m], b[n], acc[m][n], 0, 0, 0);
        __syncthreads();
    }

    int col  = lane & 15;
    int rsub = (lane >> 4) * 4;

    if (EPI == 0) {
#pragma unroll
        for (int m = 0; m < 4; ++m) {
            int gm0 = bm + wr * 64 + m * 16 + rsub;
#pragma unroll
            for (int n = 0; n < 4; ++n) {
                int gn = bn + wc * 64 + n * 16 + col;
                if (gn >= N) continue;
#pragma unroll
                for (int j = 0; j < 4; ++j) {
                    int gm = gm0 + j;
                    if (gm >= M) continue;
                    unsigned short b = f2bf(acc[m][n][j]);
                    if (gn < nsplit) C0[(size_t)gm * ld0 + gn] = b;
                    else             C1[(size_t)gm * ld1 + (gn - nsplit)] = b;
                }
            }
        }
    } else {
        // permuted writes; this thread covers pos base = bn + wc*64 + col*4
#pragma unroll
        for (int m = 0; m < 4; ++m) {
            int gm0 = bm + wr * 64 + m * 16 + rsub;
#pragma unroll
            for (int j = 0; j < 4; ++j) {
                int gm = gm0 + j;
                if (gm >= M) continue;
                float v0 = acc[m][0][j], v1 = acc[m][1][j];
                float v2 = acc[m][2][j], v3 = acc[m][3][j];
                ushort4v o;
                o[0] = f2bf(v0); o[1] = f2bf(v1); o[2] = f2bf(v2); o[3] = f2bf(v3);
                if (bn < 256) {
                    int pos = bn + wc * 64 + col * 4;
                    *(ushort4v*)&Hs[(size_t)gm * 256 + pos] = o;
                    int pk = 0;
                    pk = __builtin_amdgcn_cvt_pk_fp8_f32(v0, v1, pk, false);
                    pk = __builtin_amdgcn_cvt_pk_fp8_f32(v2, v3, pk, true);
                    *(unsigned*)&Hq[(size_t)gm * 256 + pos] = (unsigned)pk;
                } else {
                    int pos = wc * 64 + col * 4;
                    *(ushort4v*)&HmP[(size_t)gm * 128 + pos] = o;
                }
            }
        }
    }
}

// ---------------- layer 0: wave-per-node, fp8 neighbor gather + ACM epilogue ----------------
// Hq fp8 perm [256 B/row]; Hs bf16 perm [256]; HmP bf16 perm [128].
// lane's 4 true feats: c_q = (lane>>4)*64 + q*16 + (lane&15); lanes<32 = hl, >=32 = hh.

__global__ __launch_bounds__(256) void k_layer0(
        const unsigned short* __restrict__ Hs, const unsigned char* __restrict__ Hq,
        const unsigned short* __restrict__ HmP,
        const int* __restrict__ rowPtr, const unsigned short* __restrict__ colIdx,
        const float* __restrict__ dinv,
        const float* __restrict__ al, const float* __restrict__ ah,
        const float* __restrict__ am, const float* __restrict__ att,
        unsigned short* __restrict__ hout) {
    int lane = threadIdx.x & 63;
    int i = blockIdx.x * 4 + (threadIdx.x >> 6);

    int p0 = rowPtr[i], p1 = rowPtr[i + 1];
    float a0 = 0.f, a1 = 0.f, a2 = 0.f, a3 = 0.f;
    int off4 = lane * 4;
    int p = p0;
    for (; p + 7 < p1; p += 8) {
        int j[8];
#pragma unroll
        for (int q = 0; q < 8; ++q) j[q] = (int)colIdx[p + q];
        unsigned w[8];
#pragma unroll
        for (int q = 0; q < 8; ++q) w[q] = *(const unsigned*)(Hq + (size_t)j[q] * 256 + off4);
#pragma unroll
        for (int q = 0; q < 8; ++q) {
            f32x2 d0 = __builtin_amdgcn_cvt_pk_f32_fp8((int)w[q], false);
            f32x2 d1 = __builtin_amdgcn_cvt_pk_f32_fp8((int)w[q], true);
            a0 += d0.x; a1 += d0.y; a2 += d1.x; a3 += d1.y;
        }
    }
    for (; p < p1; ++p) {
        int j = (int)colIdx[p];
        unsigned w = *(const unsigned*)(Hq + (size_t)j * 256 + off4);
        f32x2 d0 = __builtin_amdgcn_cvt_pk_f32_fp8((int)w, false);
        f32x2 d1 = __builtin_amdgcn_cvt_pk_f32_fp8((int)w, true);
        a0 += d0.x; a1 += d0.y; a2 += d1.x; a3 += d1.y;
    }

    uint2 sv = *(const uint2*)(Hs + (size_t)i * 256 + off4);   // 4 bf16 self vals
    float s0 = bflo(sv.x), s1 = bfhi(sv.x), s2 = bflo(sv.y), s3 = bfhi(sv.y);
    float di = dinv[i];
    float l0 = di * (s0 + a0), l1 = di * (s1 + a1);
    float l2 = di * (s2 + a2), l3 = di * (s3 + a3);

    float ol0 = fmaxf(l0, 0.f), ol1 = fmaxf(l1, 0.f);
    float ol2 = fmaxf(l2, 0.f), ol3 = fmaxf(l3, 0.f);
    float oh0 = fmaxf(s0 - l0, 0.f), oh1 = fmaxf(s1 - l1, 0.f);
    float oh2 = fmaxf(s2 - l2, 0.f), oh3 = fmaxf(s3 - l3, 0.f);

    int c0 = ((lane >> 4) << 6) + (lane & 15);   // true feat of q=0

    float om0 = 0.f, om1 = 0.f, om2 = 0.f, om3 = 0.f;
    float prA, prM = 0.f;
    if (lane < 32) {
        uint2 hv = *(const uint2*)(HmP + (size_t)i * 128 + off4);
        om0 = fmaxf(bflo(hv.x), 0.f); om1 = fmaxf(bfhi(hv.x), 0.f);
        om2 = fmaxf(bflo(hv.y), 0.f); om3 = fmaxf(bfhi(hv.y), 0.f);
        prA = ol0 * al[c0] + ol1 * al[c0 + 16] + ol2 * al[c0 + 32] + ol3 * al[c0 + 48];
        prM = om0 * am[c0] + om1 * am[c0 + 16] + om2 * am[c0 + 32] + om3 * am[c0 + 48];
    } else {
        int ch = c0 - 128;
        prA = oh0 * ah[ch] + oh1 * ah[ch + 16] + oh2 * ah[ch + 32] + oh3 * ah[ch + 48];
    }

#pragma unroll
    for (int d = 1; d < 32; d <<= 1) prA += __shfl_xor(prA, d);
#pragma unroll
    for (int d = 1; d < 32; d <<= 1) prM += __shfl_xor(prM, d);
    float g0 = __shfl(prA, 0);
    float g1 = __shfl(prA, 32);
    float g2 = __shfl(prM, 0);

    float sg0 = sigmoidf_(g0), sg1 = sigmoidf_(g1), sg2 = sigmoidf_(g2);
    const float inv3 = (1.0f / 3.0f);
    float e0 = (sg0 * att[0] + sg1 * att[3] + sg2 * att[6]) * inv3;
    float e1 = (sg0 * att[1] + sg1 * att[4] + sg2 * att[7]) * inv3;
    float e2 = (sg0 * att[2] + sg1 * att[5] + sg2 * att[8]) * inv3;
    float mx = fmaxf(e0, fmaxf(e1, e2));
    float x0 = expf(e0 - mx), x1 = expf(e1 - mx), x2 = expf(e2 - mx);
    float inv = 1.0f / (x0 + x1 + x2);
    float c0f = 3.0f * inv * x0, c1f = 3.0f * inv * x1, c2f = 3.0f * inv * x2;

    int src = lane | 32;
    float th0 = __shfl(oh0, src), th1 = __shfl(oh1, src);
    float th2 = __shfl(oh2, src), th3 = __shfl(oh3, src);

    if (lane < 32) {
        // hbuf permuted: pos p = lane*4+q -> true feat c_q (matches W1t k-perm)
        ushort4v o;
        o[0] = f2bf(c0f * ol0 + c1f * th0 + c2f * om0);
        o[1] = f2bf(c0f * ol1 + c1f * th1 + c2f * om1);
        o[2] = f2bf(c0f * ol2 + c1f * th2 + c2f * om2);
        o[3] = f2bf(c0f * ol3 + c1f * th3 + c2f * om3);
        *(ushort4v*)&hout[(size_t)i * 128 + off4] = o;
    }
}

// ---------------- layer 1: wave-per-node aggregate + ACM epilogue ----------------
// H1g[i][c] bf16: c<40 hl, c>=40 hh (80 cols). H1m: hm (40). lanes 0..39 active.

__global__ __launch_bounds__(256) void k_layer1(
        const unsigned short* __restrict__ H1g, const unsigned short* __restrict__ H1m,
        const int* __restrict__ rowPtr, const unsigned short* __restrict__ colIdx,
        const float* __restrict__ dinv,
        const float* __restrict__ al, const float* __restrict__ ah,
        const float* __restrict__ am, const float* __restrict__ att,
        float* __restrict__ out) {
    int lane = threadIdx.x & 63;
    int i = blockIdx.x * 4 + (threadIdx.x >> 6);

    int p0 = rowPtr[i], p1 = rowPtr[i + 1];
    float a0 = 0.f, a1 = 0.f;
    int off = lane * 2;
    bool active = lane < 40;
    int p = p0;
    if (active) {
        for (; p + 7 < p1; p += 8) {
            int j[8];
#pragma unroll
            for (int q = 0; q < 8; ++q) j[q] = (int)colIdx[p + q];
            unsigned v[8];
#pragma unroll
            for (int q = 0; q < 8; ++q) v[q] = *(const unsigned*)(H1g + (size_t)j[q] * 80 + off);
#pragma unroll
            for (int q = 0; q < 8; ++q) { a0 += bflo(v[q]); a1 += bfhi(v[q]); }
        }
        for (; p < p1; ++p) {
            int j = (int)colIdx[p];
            unsigned v = *(const unsigned*)(H1g + (size_t)j * 80 + off);
            a0 += bflo(v); a1 += bfhi(v);
        }
    }

    float s0 = 0.f, s1 = 0.f;
    if (active) {
        unsigned sv = *(const unsigned*)(H1g + (size_t)i * 80 + off);
        s0 = bflo(sv); s1 = bfhi(sv);
    }
    float di = dinv[i];
    float l0 = di * (s0 + a0), l1 = di * (s1 + a1);

    float ol0 = fmaxf(l0, 0.f), ol1 = fmaxf(l1, 0.f);
    float oh0 = fmaxf(s0 - l0, 0.f), oh1 = fmaxf(s1 - l1, 0.f);

    float om0 = 0.f, om1 = 0.f;
    float r0 = 0.f, r1 = 0.f, r2 = 0.f;
    if (lane < 20) {
        unsigned hv = *(const unsigned*)(H1m + (size_t)i * 40 + off);
        om0 = fmaxf(bflo(hv), 0.f); om1 = fmaxf(bfhi(hv), 0.f);
        float2 alv = *(const float2*)(al + off);
        float2 amv = *(const float2*)(am + off);
        r0 = ol0 * alv.x + ol1 * alv.y;
        r2 = om0 * amv.x + om1 * amv.y;
    } else if (lane < 40) {
        float2 ahv = *(const float2*)(ah + (off - 40));
        r1 = oh0 * ahv.x + oh1 * ahv.y;
    }

#pragma unroll
    for (int d = 1; d < 64; d <<= 1) r0 += __shfl_xor(r0, d);
#pragma unroll
    for (int d = 1; d < 64; d <<= 1) r1 += __shfl_xor(r1, d);
#pragma unroll
    for (int d = 1; d < 64; d <<= 1) r2 += __shfl_xor(r2, d);

    float sg0 = sigmoidf_(r0), sg1 = sigmoidf_(r1), sg2 = sigmoidf_(r2);
    const float inv3 = (1.0f / 3.0f);
    float e0 = (sg0 * att[0] + sg1 * att[3] + sg2 * att[6]) * inv3;
    float e1 = (sg0 * att[1] + sg1 * att[4] + sg2 * att[7]) * inv3;
    float e2 = (sg0 * att[2] + sg1 * att[5] + sg2 * att[8]) * inv3;
    float mx = fmaxf(e0, fmaxf(e1, e2));
    float x0 = expf(e0 - mx), x1 = expf(e1 - mx), x2 = expf(e2 - mx);
    float inv = 1.0f / (x0 + x1 + x2);
    float c0 = 3.0f * inv * x0, c1 = 3.0f * inv * x1, c2 = 3.0f * inv * x2;

    int src = (lane + 20) & 63;
    float th0 = __shfl(oh0, src), th1 = __shfl(oh1, src);

    if (lane < 20) {
        float2 o;
        o.x = c0 * ol0 + c1 * th0 + c2 * om0;
        o.y = c0 * ol1 + c1 * th1 + c2 * om1;
        *(float2*)&out[(size_t)i * 40 + off] = o;
    }
}

// ---------------- launch ----------------

extern "C" void kernel_launch(void* const* d_in, const int* in_sizes, int n_in,
                              void* d_out, int out_size, void* d_ws, size_t ws_size,
                              hipStream_t stream) {
    const float* x    = (const float*)d_in[0];
    const int*   ei   = (const int*)d_in[1];
    const float* Wl0  = (const float*)d_in[2];
    const float* Wh0  = (const float*)d_in[3];
    const float* Wm0  = (const float*)d_in[4];
    const float* al0  = (const float*)d_in[5];
    const float* ah0  = (const float*)d_in[6];
    const float* am0  = (const float*)d_in[7];
    const float* att0 = (const float*)d_in[8];
    const float* Wl1  = (const float*)d_in[9];
    const float* Wh1  = (const float*)d_in[10];
    const float* Wm1  = (const float*)d_in[11];
    const float* al1  = (const float*)d_in[12];
    const float* ah1  = (const float*)d_in[13];
    const float* am1  = (const float*)d_in[14];
    const float* att1 = (const float*)d_in[15];
    float* out = (float*)d_out;

    char* ws = (char*)d_ws;
    size_t off = 0;
    auto alloc = [&](size_t bytes) -> char* {
        char* p = ws + off;
        off += (bytes + 255) & ~(size_t)255;
        return p;
    };
    int*      rowPtr  = (int*)     alloc((size_t)(N_NODES + 1) * 4);
    int*      blkTot  = (int*)     alloc(256 * 4);
    unsigned* segHist = (unsigned*)alloc((size_t)SEG * NWORD * 4);   // 12.8 MB
    unsigned short* rank   = (unsigned short*)alloc((size_t)N_EDGES * 2);
    unsigned*       rc     = (unsigned*)      alloc((size_t)N_EDGES * 4);
    unsigned short* colIdx = (unsigned short*)alloc((size_t)N_EDGES * 2);
    float* dinv   = (float*)alloc((size_t)N_NODES * 4);
    unsigned short* W0t  = (unsigned short*)alloc((size_t)W0N * IN_F * 2);
    unsigned short* W1t  = (unsigned short*)alloc((size_t)W1N * HID_F * 2);
    unsigned short* xb   = (unsigned short*)alloc((size_t)N_NODES * IN_F * 2);
    unsigned short* Hs   = (unsigned short*)alloc((size_t)N_NODES * 256 * 2);
    unsigned char*  Hq   = (unsigned char*) alloc((size_t)N_NODES * 256);
    unsigned short* HmP  = (unsigned short*)alloc((size_t)N_NODES * 128 * 2);
    unsigned short* H1g  = (unsigned short*)alloc((size_t)N_NODES * 80 * 2);
    unsigned short* H1m  = (unsigned short*)alloc((size_t)N_NODES * 40 * 2);
    unsigned short* hbuf = (unsigned short*)alloc((size_t)N_NODES * HID_F * 2);

    // 1. segmented LDS histogram (deg + rank + rc, no global atomics)
    k_hist<<<SEG, 256, 0, stream>>>(ei, segHist, rank, rc);
    // 2. fused prep (x->bf16, W packs)
    k_prep<<<PREPB, 256, 0, stream>>>(x, xb, Wl0, Wh0, Wm0, W0t,
                                      Wl1, Wh1, Wm1, W1t);
    // 3. segment-offset scan + local rowPtr + dinv
    k_scanseg<<<WB, 256, 0, stream>>>(segHist, rowPtr, dinv, blkTot);
    // 4-5. block-offset scan + apply
    k_scan2<<<1, 256, 0, stream>>>(blkTot);
    k_scan3<<<NB, 256, 0, stream>>>(blkTot, rowPtr);
    // 6. GEMM0 (layer-0 epilogue: Hs/Hq/HmP) with fused atomic-free CSR fill
    {
        dim3 grid(3 + 8, (N_NODES + 127) / 128);
        k_gemm_fill<1><<<grid, 256, 0, stream>>>(xb, W0t,
                                                 nullptr, 0, nullptr, 0, 0,
                                                 Hs, Hq, HmP,
                                                 N_NODES, W0N, IN_F, 3,
                                                 rc, rank, rowPtr,
                                                 (const unsigned short*)segHist, colIdx);
    }
    // 7. layer-0 aggregate + epilogue
    k_layer0<<<N_NODES / 4, 256, 0, stream>>>(Hs, Hq, HmP, rowPtr, colIdx, dinv,
                                              al0, ah0, am0, att0, hbuf);
    // 8. GEMM1 (plain epilogue -> H1g/H1m)
    {
        dim3 grid(1, (N_NODES + 127) / 128);
        k_gemm_fill<0><<<grid, 256, 0, stream>>>(hbuf, W1t,
                                                 H1g, 80, H1m, 40, 80,
                                                 nullptr, nullptr, nullptr,
                                                 N_NODES, W1N, HID_F, 1,
                                                 nullptr, nullptr, nullptr, nullptr, nullptr);
    }
    // 9. layer-1 aggregate + epilogue
    k_layer1<<<N_NODES / 4, 256, 0, stream>>>(H1g, H1m, rowPtr, colIdx, dinv,
                                              al1, ah1, am1, att1, out);
}

// Round 10
// 196.899 us; speedup vs baseline: 1.5177x; 1.0249x over previous
//
#include <hip/hip_runtime.h>
#include <math.h>

#define N_NODES 50000
#define N_EDGES 800000
#define IN_F    256
#define HID_F   128
#define OUT_F   40
#define W0N     (3*HID_F)   // 384
#define W1N     (3*OUT_F)   // 120
#define NB      ((N_NODES + 255) / 256)   // 196

#define SEG     128
#define EPB     (N_EDGES / SEG)           // 6250 edges per segment
#define NWORD   (N_NODES / 2)             // 25000 packed words (2 nodes/word)
#define WB      ((NWORD + 255) / 256)     // 98 scanseg blocks

// k_prep block ranges (convert + weight packs only)
#define XB   ((N_NODES * IN_F) / (256 * 16))   // 3125
#define P0B  ((IN_F * W0N) / 256)              // 384
#define P1B  ((HID_F * W1N) / 256)             // 60
#define PREPB (XB + P0B + P1B)                 // 3569

typedef __attribute__((ext_vector_type(8))) unsigned short ushort8;
typedef __attribute__((ext_vector_type(4))) unsigned short ushort4v;
typedef __attribute__((ext_vector_type(8))) __bf16 bf16x8;
typedef __attribute__((ext_vector_type(4))) float f32x4;
typedef __attribute__((ext_vector_type(2))) float f32x2;

static __device__ __forceinline__ float sigmoidf_(float x) {
    return 1.0f / (1.0f + expf(-x));
}

static __device__ __forceinline__ unsigned short f2bf(float f) {
    unsigned u = __float_as_uint(f);
    u += 0x7FFFu + ((u >> 16) & 1u);
    return (unsigned short)(u >> 16);
}

static __device__ __forceinline__ float bflo(unsigned u) { return __uint_as_float(u << 16); }
static __device__ __forceinline__ float bfhi(unsigned u) { return __uint_as_float(u & 0xffff0000u); }
static __device__ __forceinline__ int rfl(int v) { return __builtin_amdgcn_readfirstlane(v); }

// ------- segmented LDS histogram: deg counts + local rank + rc, NO global atomics -------

__global__ __launch_bounds__(256) void k_hist(
        const int* __restrict__ ei, unsigned* __restrict__ segHist,
        unsigned short* __restrict__ rank, unsigned* __restrict__ rc) {
    __shared__ unsigned hist[NWORD];   // 100 KB: 2 u16 counters per word
    int t = threadIdx.x, seg = blockIdx.x;
    for (int i = t; i < NWORD; i += 256) hist[i] = 0;
    __syncthreads();
    int base = seg * EPB;
    for (int k = t; k < EPB; k += 256) {
        int e = base + k;
        int r = ei[e];
        int c = ei[N_EDGES + e];
        unsigned old = atomicAdd(&hist[r >> 1], (r & 1) ? 0x10000u : 1u);
        unsigned lr = (r & 1) ? (old >> 16) : (old & 0xffffu);
        rank[e] = (unsigned short)lr;
        rc[e] = ((unsigned)r << 16) | (unsigned)c;
    }
    __syncthreads();
    unsigned* dst = segHist + (size_t)seg * NWORD;
    for (int i = t; i < NWORD; i += 256) dst[i] = hist[i];
}

// ------- scanseg: in-place segHist -> per-segment offsets; local rowPtr + dinv + blkTot -------

__global__ __launch_bounds__(256) void k_scanseg(
        unsigned* __restrict__ segHist, int* __restrict__ rowPtr,
        float* __restrict__ dinv, int* __restrict__ blkTot) {
    __shared__ int s[256];
    int t = threadIdx.x;
    int w = blockIdx.x * 256 + t;    // packed word = nodes 2w, 2w+1
    int cum0 = 0, cum1 = 0;
    if (w < NWORD) {
        for (int sg = 0; sg < SEG; ++sg) {
            size_t idx = (size_t)sg * NWORD + w;
            unsigned h = segHist[idx];
            segHist[idx] = ((unsigned)cum1 << 16) | (unsigned)cum0;  // offset-before
            cum0 += (int)(h & 0xffffu);
            cum1 += (int)(h >> 16);
        }
    }
    int deg0 = cum0, deg1 = cum1;
    int pair = deg0 + deg1;
    s[t] = pair; __syncthreads();
    for (int d = 1; d < 256; d <<= 1) {
        int x = (t >= d) ? s[t - d] : 0;
        __syncthreads();
        s[t] += x;
        __syncthreads();
    }
    int basep = s[t] - pair;   // exclusive prefix within block
    if (w < NWORD) {
        rowPtr[2 * w]     = basep;
        rowPtr[2 * w + 1] = basep + deg0;
        dinv[2 * w]     = 1.0f / (1.0f + (float)deg0);
        dinv[2 * w + 1] = 1.0f / (1.0f + (float)deg1);
    }
    if (t == 255) blkTot[blockIdx.x] = s[255];
}

__global__ void k_scan2(int* __restrict__ blk) {
    __shared__ int s[256];
    int t = threadIdx.x;
    int v = (t < WB) ? blk[t] : 0;
    s[t] = v; __syncthreads();
    for (int d = 1; d < 256; d <<= 1) {
        int x = (t >= d) ? s[t - d] : 0;
        __syncthreads();
        s[t] += x;
        __syncthreads();
    }
    if (t < WB) blk[t] = s[t] - v;
}

__global__ void k_scan3(const int* __restrict__ blkOff, int* __restrict__ rowPtr) {
    int t = threadIdx.x;
    int gid = blockIdx.x * 256 + t;
    if (gid < N_NODES) rowPtr[gid] += blkOff[gid >> 9];   // 512 nodes per scanseg block
    if (gid == 0) rowPtr[N_NODES] = N_EDGES;
}

// ------- fused prep: x->bf16 | pack W0^T | pack W1^T(k-perm) -------

__global__ __launch_bounds__(256) void k_prep(
        const float* __restrict__ x, unsigned short* __restrict__ xb,
        const float* __restrict__ Wl0, const float* __restrict__ Wh0,
        const float* __restrict__ Wm0, unsigned short* __restrict__ W0t,
        const float* __restrict__ Wl1, const float* __restrict__ Wh1,
        const float* __restrict__ Wm1, unsigned short* __restrict__ W1t) {
    int b = blockIdx.x, t = threadIdx.x;
    if (b < XB) {
        size_t idx = (size_t)b * 4096 + t * 16;
        float4 f0 = *(const float4*)(x + idx);
        float4 f1 = *(const float4*)(x + idx + 4);
        float4 f2 = *(const float4*)(x + idx + 8);
        float4 f3 = *(const float4*)(x + idx + 12);
        ushort8 u0, u1;
        u0[0]=f2bf(f0.x); u0[1]=f2bf(f0.y); u0[2]=f2bf(f0.z); u0[3]=f2bf(f0.w);
        u0[4]=f2bf(f1.x); u0[5]=f2bf(f1.y); u0[6]=f2bf(f1.z); u0[7]=f2bf(f1.w);
        u1[0]=f2bf(f2.x); u1[1]=f2bf(f2.y); u1[2]=f2bf(f2.z); u1[3]=f2bf(f2.w);
        u1[4]=f2bf(f3.x); u1[5]=f2bf(f3.y); u1[6]=f2bf(f3.z); u1[7]=f2bf(f3.w);
        *(ushort8*)(xb + idx)     = u0;
        *(ushort8*)(xb + idx + 8) = u1;
    } else if (b < XB + P0B) {
        int i = (b - XB) * 256 + t;
        int n = i / IN_F, k = i % IN_F;
        float v;
        if (n < HID_F)            v = Wl0[k * HID_F + n];
        else if (n < 2 * HID_F)   v = Wh0[k * HID_F + (n - HID_F)];
        else                      v = Wm0[k * HID_F + (n - 2 * HID_F)];
        W0t[i] = f2bf(v);
    } else {
        int i = (b - XB - P0B) * 256 + t;
        int n = i / HID_F, kp = i % HID_F;
        // k-dim permuted to match hbuf's permuted layout: feat = g*64 + q*16 + c
        int k = ((kp >> 6) << 6) + ((kp & 3) << 4) + ((kp >> 2) & 15);
        float v;
        if (n < OUT_F)            v = Wl1[k * OUT_F + n];
        else if (n < 2 * OUT_F)   v = Wh1[k * OUT_F + (n - OUT_F)];
        else                      v = Wm1[k * OUT_F + (n - 2 * OUT_F)];
        W1t[i] = f2bf(v);
    }
}

// ---------------- bf16 MFMA GEMM + optional fused atomic-free CSR-fill ----------------
// tile 128x128, BK=32, 4 waves (2x2).
// EPI=0 (GEMM1): bf16 split write cols [0,nsplit)->C0(ld0), rest->C1(ld1);
//                plus fp8 byte store to Cq[gm*nsplit+gn] for gn<nsplit.
// EPI=1 (GEMM0): Hs (bf16 perm), Hq (fp8 perm), HmP (bf16 perm).
//   permuted pos within 64-col group: pos = col*4 + n  <->  feat = n*16 + col

#define BKP 40   // 32 + 8 pad

template<int EPI>
__global__ __launch_bounds__(256) void k_gemm_fill(
        const unsigned short* __restrict__ A, const unsigned short* __restrict__ Bt,
        unsigned short* __restrict__ C0, int ld0,
        unsigned short* __restrict__ C1, int ld1, int nsplit,
        unsigned char* __restrict__ Cq,
        unsigned short* __restrict__ Hs, unsigned char* __restrict__ Hq,
        unsigned short* __restrict__ HmP,
        int M, int N, int K, int nxt,
        const unsigned* __restrict__ rc, const unsigned short* __restrict__ rank,
        const int* __restrict__ rowPtr, const unsigned short* __restrict__ segOff,
        unsigned short* __restrict__ colIdx) {
    __shared__ unsigned short As[128 * BKP];
    __shared__ unsigned short Bs[128 * BKP];
    int tid  = threadIdx.x;

    if ((int)blockIdx.x >= nxt) {
        int fid = (blockIdx.x - nxt) * gridDim.y + blockIdx.y;
        int e = fid * 256 + tid;
        if (e < N_EDGES) {
            unsigned x = rc[e];
            int r = (int)(x >> 16);
            int seg = e / EPB;
            int pos = rowPtr[r] + (int)segOff[(size_t)seg * N_NODES + r] + (int)rank[e];
            colIdx[pos] = (unsigned short)(x & 0xffffu);
        }
        return;
    }

    int lane = tid & 63, wid = tid >> 6;
    int wr = wid >> 1, wc = wid & 1;
    int bm = blockIdx.y * 128, bn = blockIdx.x * 128;

    int srow = tid >> 1;
    int scol = (tid & 1) * 16;

    int garow = min(bm + srow, M - 1);
    int gbrow = min(bn + srow, N - 1);

    f32x4 acc[4][4];
#pragma unroll
    for (int m = 0; m < 4; ++m)
#pragma unroll
        for (int n = 0; n < 4; ++n)
            acc[m][n] = (f32x4)(0.0f);

    int kg = (lane >> 4) * 8;
    int rA = wr * 64 + (lane & 15);
    int rB = wc * 64 + (lane & 15);

    for (int k0 = 0; k0 < K; k0 += 32) {
        {
            const unsigned short* src = A + (size_t)garow * K + k0 + scol;
            *(ushort8*)&As[srow * BKP + scol]     = *(const ushort8*)(src);
            *(ushort8*)&As[srow * BKP + scol + 8] = *(const ushort8*)(src + 8);
        }
        {
            const unsigned short* src = Bt + (size_t)gbrow * K + k0 + scol;
            *(ushort8*)&Bs[srow * BKP + scol]     = *(const ushort8*)(src);
            *(ushort8*)&Bs[srow * BKP + scol + 8] = *(const ushort8*)(src + 8);
        }
        __syncthreads();

        bf16x8 a[4], b[4];
#pragma unroll
        for (int m = 0; m < 4; ++m)
            a[m] = __builtin_bit_cast(bf16x8, *(const ushort8*)&As[(rA + m * 16) * BKP + kg]);
#pragma unroll
        for (int n = 0; n < 4; ++n)
            b[n] = __builtin_bit_cast(bf16x8, *(const ushort8*)&Bs[(rB + n * 16) * BKP + kg]);
#pragma unroll
        for (int m = 0; m < 4; ++m)
#pragma unroll
            for (int n = 0; n < 4; ++n)
                acc[m][n] = __builtin_amdgcn_mfma_f32_16x16x32_bf16(a[m], b[n], acc[m][n], 0, 0, 0);
        __syncthreads();
    }

    int col  = lane & 15;
    int rsub = (lane >> 4) * 4;

    if (EPI == 0) {
#pragma unroll
        for (int m = 0; m < 4; ++m) {
            int gm0 = bm + wr * 64 + m * 16 + rsub;
#pragma unroll
            for (int n = 0; n < 4; ++n) {
                int gn = bn + wc * 64 + n * 16 + col;
                if (gn >= N) continue;
#pragma unroll
                for (int j = 0; j < 4; ++j) {
                    int gm = gm0 + j;
                    if (gm >= M) continue;
                    float v = acc[m][n][j];
                    unsigned short b = f2bf(v);
                    if (gn < nsplit) {
                        C0[(size_t)gm * ld0 + gn] = b;
                        int pk = __builtin_amdgcn_cvt_pk_fp8_f32(v, v, 0, false);
                        Cq[(size_t)gm * nsplit + gn] = (unsigned char)(pk & 0xff);
                    } else {
                        C1[(size_t)gm * ld1 + (gn - nsplit)] = b;
                    }
                }
            }
        }
    } else {
        // permuted writes; this thread covers pos base = bn + wc*64 + col*4
#pragma unroll
        for (int m = 0; m < 4; ++m) {
            int gm0 = bm + wr * 64 + m * 16 + rsub;
#pragma unroll
            for (int j = 0; j < 4; ++j) {
                int gm = gm0 + j;
                if (gm >= M) continue;
                float v0 = acc[m][0][j], v1 = acc[m][1][j];
                float v2 = acc[m][2][j], v3 = acc[m][3][j];
                ushort4v o;
                o[0] = f2bf(v0); o[1] = f2bf(v1); o[2] = f2bf(v2); o[3] = f2bf(v3);
                if (bn < 256) {
                    int pos = bn + wc * 64 + col * 4;
                    *(ushort4v*)&Hs[(size_t)gm * 256 + pos] = o;
                    int pk = 0;
                    pk = __builtin_amdgcn_cvt_pk_fp8_f32(v0, v1, pk, false);
                    pk = __builtin_amdgcn_cvt_pk_fp8_f32(v2, v3, pk, true);
                    *(unsigned*)&Hq[(size_t)gm * 256 + pos] = (unsigned)pk;
                } else {
                    int pos = wc * 64 + col * 4;
                    *(ushort4v*)&HmP[(size_t)gm * 128 + pos] = o;
                }
            }
        }
    }
}

// ---------------- layer 0: wave-per-node, scalarized fp8 gather + ACM epilogue ----------------
// Hq fp8 perm [256 B/row]; Hs bf16 perm [256]; HmP bf16 perm [128].
// lane's 4 true feats: c_q = (lane>>4)*64 + q*16 + (lane&15); lanes<32 = hl, >=32 = hh.

__global__ __launch_bounds__(256) void k_layer0(
        const unsigned short* __restrict__ Hs, const unsigned char* __restrict__ Hq,
        const unsigned short* __restrict__ HmP,
        const int* __restrict__ rowPtr, const unsigned short* __restrict__ colIdx,
        const float* __restrict__ dinv,
        const float* __restrict__ al, const float* __restrict__ ah,
        const float* __restrict__ am, const float* __restrict__ att,
        unsigned short* __restrict__ hout) {
    int lane = threadIdx.x & 63;
    int i = blockIdx.x * 4 + (threadIdx.x >> 6);

    int p0 = rfl(rowPtr[i]);
    int p1 = rfl(rowPtr[i + 1]);
    float a0 = 0.f, a1 = 0.f, a2 = 0.f, a3 = 0.f;
    int off4 = lane * 4;

    auto acc1 = [&](unsigned j) {
        const unsigned char* row = Hq + ((size_t)(j << 8));   // j*256, scalar
        unsigned w = *(const unsigned*)(row + off4);
        f32x2 d0 = __builtin_amdgcn_cvt_pk_f32_fp8((int)w, false);
        f32x2 d1 = __builtin_amdgcn_cvt_pk_f32_fp8((int)w, true);
        a0 += d0.x; a1 += d0.y; a2 += d1.x; a3 += d1.y;
    };

    int p = p0;
    while ((p & 3) != 0 && p < p1) {                  // peel to uint2 alignment
        acc1((unsigned)rfl((int)colIdx[p]));
        ++p;
    }
    for (; p + 7 < p1; p += 8) {
        uint2 ca = *(const uint2*)(colIdx + p);
        uint2 cb = *(const uint2*)(colIdx + p + 4);
        unsigned w0 = (unsigned)rfl((int)ca.x);
        unsigned w1 = (unsigned)rfl((int)ca.y);
        unsigned w2 = (unsigned)rfl((int)cb.x);
        unsigned w3 = (unsigned)rfl((int)cb.y);
        acc1(w0 & 0xffffu); acc1(w0 >> 16);
        acc1(w1 & 0xffffu); acc1(w1 >> 16);
        acc1(w2 & 0xffffu); acc1(w2 >> 16);
        acc1(w3 & 0xffffu); acc1(w3 >> 16);
    }
    for (; p + 3 < p1; p += 4) {
        uint2 ca = *(const uint2*)(colIdx + p);
        unsigned w0 = (unsigned)rfl((int)ca.x);
        unsigned w1 = (unsigned)rfl((int)ca.y);
        acc1(w0 & 0xffffu); acc1(w0 >> 16);
        acc1(w1 & 0xffffu); acc1(w1 >> 16);
    }
    for (; p < p1; ++p) {
        acc1((unsigned)rfl((int)colIdx[p]));
    }

    uint2 sv = *(const uint2*)(Hs + (size_t)i * 256 + off4);   // 4 bf16 self vals
    float s0 = bflo(sv.x), s1 = bfhi(sv.x), s2 = bflo(sv.y), s3 = bfhi(sv.y);
    float di = dinv[i];
    float l0 = di * (s0 + a0), l1 = di * (s1 + a1);
    float l2 = di * (s2 + a2), l3 = di * (s3 + a3);

    float ol0 = fmaxf(l0, 0.f), ol1 = fmaxf(l1, 0.f);
    float ol2 = fmaxf(l2, 0.f), ol3 = fmaxf(l3, 0.f);
    float oh0 = fmaxf(s0 - l0, 0.f), oh1 = fmaxf(s1 - l1, 0.f);
    float oh2 = fmaxf(s2 - l2, 0.f), oh3 = fmaxf(s3 - l3, 0.f);

    int c0 = ((lane >> 4) << 6) + (lane & 15);   // true feat of q=0

    float om0 = 0.f, om1 = 0.f, om2 = 0.f, om3 = 0.f;
    float prA, prM = 0.f;
    if (lane < 32) {
        uint2 hv = *(const uint2*)(HmP + (size_t)i * 128 + off4);
        om0 = fmaxf(bflo(hv.x), 0.f); om1 = fmaxf(bfhi(hv.x), 0.f);
        om2 = fmaxf(bflo(hv.y), 0.f); om3 = fmaxf(bfhi(hv.y), 0.f);
        prA = ol0 * al[c0] + ol1 * al[c0 + 16] + ol2 * al[c0 + 32] + ol3 * al[c0 + 48];
        prM = om0 * am[c0] + om1 * am[c0 + 16] + om2 * am[c0 + 32] + om3 * am[c0 + 48];
    } else {
        int ch = c0 - 128;
        prA = oh0 * ah[ch] + oh1 * ah[ch + 16] + oh2 * ah[ch + 32] + oh3 * ah[ch + 48];
    }

#pragma unroll
    for (int d = 1; d < 32; d <<= 1) prA += __shfl_xor(prA, d);
#pragma unroll
    for (int d = 1; d < 32; d <<= 1) prM += __shfl_xor(prM, d);
    float g0 = __shfl(prA, 0);
    float g1 = __shfl(prA, 32);
    float g2 = __shfl(prM, 0);

    float sg0 = sigmoidf_(g0), sg1 = sigmoidf_(g1), sg2 = sigmoidf_(g2);
    const float inv3 = (1.0f / 3.0f);
    float e0 = (sg0 * att[0] + sg1 * att[3] + sg2 * att[6]) * inv3;
    float e1 = (sg0 * att[1] + sg1 * att[4] + sg2 * att[7]) * inv3;
    float e2 = (sg0 * att[2] + sg1 * att[5] + sg2 * att[8]) * inv3;
    float mx = fmaxf(e0, fmaxf(e1, e2));
    float x0 = expf(e0 - mx), x1 = expf(e1 - mx), x2 = expf(e2 - mx);
    float inv = 1.0f / (x0 + x1 + x2);
    float c0f = 3.0f * inv * x0, c1f = 3.0f * inv * x1, c2f = 3.0f * inv * x2;

    int src = lane | 32;
    float th0 = __shfl(oh0, src), th1 = __shfl(oh1, src);
    float th2 = __shfl(oh2, src), th3 = __shfl(oh3, src);

    if (lane < 32) {
        // hbuf permuted: pos p = lane*4+q -> true feat c_q (matches W1t k-perm)
        ushort4v o;
        o[0] = f2bf(c0f * ol0 + c1f * th0 + c2f * om0);
        o[1] = f2bf(c0f * ol1 + c1f * th1 + c2f * om1);
        o[2] = f2bf(c0f * ol2 + c1f * th2 + c2f * om2);
        o[3] = f2bf(c0f * ol3 + c1f * th3 + c2f * om3);
        *(ushort4v*)&hout[(size_t)i * 128 + off4] = o;
    }
}

// ---------------- layer 1: wave-per-node, scalarized fp8 gather + ACM epilogue ----------------
// H1q fp8 plain [80 B/row]; H1g bf16 plain [80] (self); H1m bf16 [40].
// lane l<20 covers feats 4l..4l+3 (feats 0-39 = hl on lanes 0-9, 40-79 = hh on 10-19).

__global__ __launch_bounds__(256) void k_layer1(
        const unsigned short* __restrict__ H1g, const unsigned char* __restrict__ H1q,
        const unsigned short* __restrict__ H1m,
        const int* __restrict__ rowPtr, const unsigned short* __restrict__ colIdx,
        const float* __restrict__ dinv,
        const float* __restrict__ al, const float* __restrict__ ah,
        const float* __restrict__ am, const float* __restrict__ att,
        float* __restrict__ out) {
    int lane = threadIdx.x & 63;
    int i = blockIdx.x * 4 + (threadIdx.x >> 6);

    int p0 = rfl(rowPtr[i]);
    int p1 = rfl(rowPtr[i + 1]);
    float a0 = 0.f, a1 = 0.f, a2 = 0.f, a3 = 0.f;
    int off4 = lane * 4;
    bool active = lane < 20;

    auto acc1 = [&](unsigned j) {
        const unsigned char* row = H1q + (size_t)(j * 80u);   // scalar
        unsigned w = *(const unsigned*)(row + off4);
        f32x2 d0 = __builtin_amdgcn_cvt_pk_f32_fp8((int)w, false);
        f32x2 d1 = __builtin_amdgcn_cvt_pk_f32_fp8((int)w, true);
        a0 += d0.x; a1 += d0.y; a2 += d1.x; a3 += d1.y;
    };

    if (active) {
        int p = p0;
        while ((p & 3) != 0 && p < p1) {
            acc1((unsigned)rfl((int)colIdx[p]));
            ++p;
        }
        for (; p + 7 < p1; p += 8) {
            uint2 ca = *(const uint2*)(colIdx + p);
            uint2 cb = *(const uint2*)(colIdx + p + 4);
            unsigned w0 = (unsigned)rfl((int)ca.x);
            unsigned w1 = (unsigned)rfl((int)ca.y);
            unsigned w2 = (unsigned)rfl((int)cb.x);
            unsigned w3 = (unsigned)rfl((int)cb.y);
            acc1(w0 & 0xffffu); acc1(w0 >> 16);
            acc1(w1 & 0xffffu); acc1(w1 >> 16);
            acc1(w2 & 0xffffu); acc1(w2 >> 16);
            acc1(w3 & 0xffffu); acc1(w3 >> 16);
        }
        for (; p + 3 < p1; p += 4) {
            uint2 ca = *(const uint2*)(colIdx + p);
            unsigned w0 = (unsigned)rfl((int)ca.x);
            unsigned w1 = (unsigned)rfl((int)ca.y);
            acc1(w0 & 0xffffu); acc1(w0 >> 16);
            acc1(w1 & 0xffffu); acc1(w1 >> 16);
        }
        for (; p < p1; ++p) {
            acc1((unsigned)rfl((int)colIdx[p]));
        }
    }

    float s0 = 0.f, s1 = 0.f, s2 = 0.f, s3 = 0.f;
    if (active) {
        uint2 sv = *(const uint2*)(H1g + (size_t)i * 80 + off4);  // 4 bf16 self
        s0 = bflo(sv.x); s1 = bfhi(sv.x); s2 = bflo(sv.y); s3 = bfhi(sv.y);
    }
    float di = dinv[i];
    float l0 = di * (s0 + a0), l1 = di * (s1 + a1);
    float l2 = di * (s2 + a2), l3 = di * (s3 + a3);

    float ol0 = fmaxf(l0, 0.f), ol1 = fmaxf(l1, 0.f);
    float ol2 = fmaxf(l2, 0.f), ol3 = fmaxf(l3, 0.f);
    float oh0 = fmaxf(s0 - l0, 0.f), oh1 = fmaxf(s1 - l1, 0.f);
    float oh2 = fmaxf(s2 - l2, 0.f), oh3 = fmaxf(s3 - l3, 0.f);

    float om0 = 0.f, om1 = 0.f, om2 = 0.f, om3 = 0.f;
    float r0 = 0.f, r1 = 0.f, r2 = 0.f;
    if (lane < 10) {
        uint2 hv = *(const uint2*)(H1m + (size_t)i * 40 + off4);
        om0 = fmaxf(bflo(hv.x), 0.f); om1 = fmaxf(bfhi(hv.x), 0.f);
        om2 = fmaxf(bflo(hv.y), 0.f); om3 = fmaxf(bfhi(hv.y), 0.f);
        float4 alv = *(const float4*)(al + off4);
        float4 amv = *(const float4*)(am + off4);
        r0 = ol0 * alv.x + ol1 * alv.y + ol2 * alv.z + ol3 * alv.w;
        r2 = om0 * amv.x + om1 * amv.y + om2 * amv.z + om3 * amv.w;
    } else if (lane < 20) {
        float4 ahv = *(const float4*)(ah + (off4 - 40));
        r1 = oh0 * ahv.x + oh1 * ahv.y + oh2 * ahv.z + oh3 * ahv.w;
    }

#pragma unroll
    for (int d = 1; d < 64; d <<= 1) r0 += __shfl_xor(r0, d);
#pragma unroll
    for (int d = 1; d < 64; d <<= 1) r1 += __shfl_xor(r1, d);
#pragma unroll
    for (int d = 1; d < 64; d <<= 1) r2 += __shfl_xor(r2, d);

    float sg0 = sigmoidf_(r0), sg1 = sigmoidf_(r1), sg2 = sigmoidf_(r2);
    const float inv3 = (1.0f / 3.0f);
    float e0 = (sg0 * att[0] + sg1 * att[3] + sg2 * att[6]) * inv3;
    float e1 = (sg0 * att[1] + sg1 * att[4] + sg2 * att[7]) * inv3;
    float e2 = (sg0 * att[2] + sg1 * att[5] + sg2 * att[8]) * inv3;
    float mx = fmaxf(e0, fmaxf(e1, e2));
    float x0 = expf(e0 - mx), x1 = expf(e1 - mx), x2 = expf(e2 - mx);
    float inv = 1.0f / (x0 + x1 + x2);
    float c0 = 3.0f * inv * x0, c1 = 3.0f * inv * x1, c2 = 3.0f * inv * x2;

    // oh for output feat f (=4l+k) lives on lane l+10, same k
    int src = (lane + 10) & 63;
    float th0 = __shfl(oh0, src), th1 = __shfl(oh1, src);
    float th2 = __shfl(oh2, src), th3 = __shfl(oh3, src);

    if (lane < 10) {
        float4 o;
        o.x = c0 * ol0 + c1 * th0 + c2 * om0;
        o.y = c0 * ol1 + c1 * th1 + c2 * om1;
        o.z = c0 * ol2 + c1 * th2 + c2 * om2;
        o.w = c0 * ol3 + c1 * th3 + c2 * om3;
        *(float4*)&out[(size_t)i * 40 + off4] = o;
    }
}

// ---------------- launch ----------------

extern "C" void kernel_launch(void* const* d_in, const int* in_sizes, int n_in,
                              void* d_out, int out_size, void* d_ws, size_t ws_size,
                              hipStream_t stream) {
    const float* x    = (const float*)d_in[0];
    const int*   ei   = (const int*)d_in[1];
    const float* Wl0  = (const float*)d_in[2];
    const float* Wh0  = (const float*)d_in[3];
    const float* Wm0  = (const float*)d_in[4];
    const float* al0  = (const float*)d_in[5];
    const float* ah0  = (const float*)d_in[6];
    const float* am0  = (const float*)d_in[7];
    const float* att0 = (const float*)d_in[8];
    const float* Wl1  = (const float*)d_in[9];
    const float* Wh1  = (const float*)d_in[10];
    const float* Wm1  = (const float*)d_in[11];
    const float* al1  = (const float*)d_in[12];
    const float* ah1  = (const float*)d_in[13];
    const float* am1  = (const float*)d_in[14];
    const float* att1 = (const float*)d_in[15];
    float* out = (float*)d_out;

    char* ws = (char*)d_ws;
    size_t off = 0;
    auto alloc = [&](size_t bytes) -> char* {
        char* p = ws + off;
        off += (bytes + 255) & ~(size_t)255;
        return p;
    };
    int*      rowPtr  = (int*)     alloc((size_t)(N_NODES + 1) * 4);
    int*      blkTot  = (int*)     alloc(256 * 4);
    unsigned* segHist = (unsigned*)alloc((size_t)SEG * NWORD * 4);   // 12.8 MB
    unsigned short* rank   = (unsigned short*)alloc((size_t)N_EDGES * 2);
    unsigned*       rc     = (unsigned*)      alloc((size_t)N_EDGES * 4);
    unsigned short* colIdx = (unsigned short*)alloc((size_t)N_EDGES * 2);
    float* dinv   = (float*)alloc((size_t)N_NODES * 4);
    unsigned short* W0t  = (unsigned short*)alloc((size_t)W0N * IN_F * 2);
    unsigned short* W1t  = (unsigned short*)alloc((size_t)W1N * HID_F * 2);
    unsigned short* xb   = (unsigned short*)alloc((size_t)N_NODES * IN_F * 2);
    unsigned short* Hs   = (unsigned short*)alloc((size_t)N_NODES * 256 * 2);
    unsigned char*  Hq   = (unsigned char*) alloc((size_t)N_NODES * 256);
    unsigned short* HmP  = (unsigned short*)alloc((size_t)N_NODES * 128 * 2);
    unsigned short* H1g  = (unsigned short*)alloc((size_t)N_NODES * 80 * 2);
    unsigned char*  H1q  = (unsigned char*) alloc((size_t)N_NODES * 80 + 256);  // +pad
    unsigned short* H1m  = (unsigned short*)alloc((size_t)N_NODES * 40 * 2);
    unsigned short* hbuf = (unsigned short*)alloc((size_t)N_NODES * HID_F * 2);

    // 1. segmented LDS histogram (deg + rank + rc, no global atomics)
    k_hist<<<SEG, 256, 0, stream>>>(ei, segHist, rank, rc);
    // 2. fused prep (x->bf16, W packs)
    k_prep<<<PREPB, 256, 0, stream>>>(x, xb, Wl0, Wh0, Wm0, W0t,
                                      Wl1, Wh1, Wm1, W1t);
    // 3. segment-offset scan + local rowPtr + dinv
    k_scanseg<<<WB, 256, 0, stream>>>(segHist, rowPtr, dinv, blkTot);
    // 4-5. block-offset scan + apply
    k_scan2<<<1, 256, 0, stream>>>(blkTot);
    k_scan3<<<NB, 256, 0, stream>>>(blkTot, rowPtr);
    // 6. GEMM0 (layer-0 epilogue: Hs/Hq/HmP) with fused atomic-free CSR fill
    {
        dim3 grid(3 + 8, (N_NODES + 127) / 128);
        k_gemm_fill<1><<<grid, 256, 0, stream>>>(xb, W0t,
                                                 nullptr, 0, nullptr, 0, 0, nullptr,
                                                 Hs, Hq, HmP,
                                                 N_NODES, W0N, IN_F, 3,
                                                 rc, rank, rowPtr,
                                                 (const unsigned short*)segHist, colIdx);
    }
    // 7. layer-0 aggregate + epilogue
    k_layer0<<<N_NODES / 4, 256, 0, stream>>>(Hs, Hq, HmP, rowPtr, colIdx, dinv,
                                              al0, ah0, am0, att0, hbuf);
    // 8. GEMM1 (bf16 H1g/H1m + fp8 H1q)
    {
        dim3 grid(1, (N_NODES + 127) / 128);
        k_gemm_fill<0><<<grid, 256, 0, stream>>>(hbuf, W1t,
                                                 H1g, 80, H1m, 40, 80, H1q,
                                                 nullptr, nullptr, nullptr,
                                                 N_NODES, W1N, HID_F, 1,
                                                 nullptr, nullptr, nullptr, nullptr, nullptr);
    }
    // 9. layer-1 aggregate + epilogue
    k_layer1<<<N_NODES / 4, 256, 0, stream>>>(H1g, H1q, H1m, rowPtr, colIdx, dinv,
                                              al1, ah1, am1, att1, out);
}

// Round 11
// 189.637 us; speedup vs baseline: 1.5758x; 1.0383x over previous
//
#include <hip/hip_runtime.h>
#include <math.h>

#define N_NODES 50000
#define N_EDGES 800000
#define IN_F    256
#define HID_F   128
#define OUT_F   40
#define W0N     (3*HID_F)   // 384
#define W1N     (3*OUT_F)   // 120
#define NB      ((N_NODES + 255) / 256)   // 196

#define SEG     128
#define EPB     (N_EDGES / SEG)           // 6250 edges per segment
#define NWORD   (N_NODES / 2)             // 25000 packed words (2 nodes/word)
#define WB      ((NWORD + 255) / 256)     // 98 scanseg blocks

// k_hp block ranges: [0,SEG) hist | x convert | pack W0 | pack W1
#define XB   ((N_NODES * IN_F) / (256 * 16))   // 3125
#define P0B  ((IN_F * W0N) / 256)              // 384
#define P1B  ((HID_F * W1N) / 256)             // 60
#define HPB0 (SEG)
#define HPB1 (SEG + XB)
#define HPB2 (SEG + XB + P0B)
#define HPREPB (SEG + XB + P0B + P1B)          // 3697

typedef __attribute__((ext_vector_type(8))) unsigned short ushort8;
typedef __attribute__((ext_vector_type(4))) unsigned short ushort4v;
typedef __attribute__((ext_vector_type(8))) __bf16 bf16x8;
typedef __attribute__((ext_vector_type(4))) float f32x4;
typedef __attribute__((ext_vector_type(2))) float f32x2;

static __device__ __forceinline__ float sigmoidf_(float x) {
    return 1.0f / (1.0f + expf(-x));
}

static __device__ __forceinline__ unsigned short f2bf(float f) {
    unsigned u = __float_as_uint(f);
    u += 0x7FFFu + ((u >> 16) & 1u);
    return (unsigned short)(u >> 16);
}

static __device__ __forceinline__ float bflo(unsigned u) { return __uint_as_float(u << 16); }
static __device__ __forceinline__ float bfhi(unsigned u) { return __uint_as_float(u & 0xffff0000u); }
static __device__ __forceinline__ int rfl(int v) { return __builtin_amdgcn_readfirstlane(v); }

// ------- fused: segmented LDS histogram | x->bf16 | pack W0^T | pack W1^T(k-perm) -------

__global__ __launch_bounds__(256) void k_hp(
        const int* __restrict__ ei, unsigned* __restrict__ segHist,
        unsigned short* __restrict__ rank, unsigned* __restrict__ rc,
        const float* __restrict__ x, unsigned short* __restrict__ xb,
        const float* __restrict__ Wl0, const float* __restrict__ Wh0,
        const float* __restrict__ Wm0, unsigned short* __restrict__ W0t,
        const float* __restrict__ Wl1, const float* __restrict__ Wh1,
        const float* __restrict__ Wm1, unsigned short* __restrict__ W1t) {
    __shared__ unsigned hist[NWORD];   // 100 KB (only hist blocks touch it)
    int b = blockIdx.x, t = threadIdx.x;
    if (b < SEG) {
        int seg = b;
        for (int i = t; i < NWORD; i += 256) hist[i] = 0;
        __syncthreads();
        int base = seg * EPB;
        for (int k = t; k < EPB; k += 256) {
            int e = base + k;
            int r = ei[e];
            int c = ei[N_EDGES + e];
            unsigned old = atomicAdd(&hist[r >> 1], (r & 1) ? 0x10000u : 1u);
            unsigned lr = (r & 1) ? (old >> 16) : (old & 0xffffu);
            rank[e] = (unsigned short)lr;
            rc[e] = ((unsigned)r << 16) | (unsigned)c;
        }
        __syncthreads();
        unsigned* dst = segHist + (size_t)seg * NWORD;
        for (int i = t; i < NWORD; i += 256) dst[i] = hist[i];
    } else if (b < HPB1) {
        size_t idx = (size_t)(b - HPB0) * 4096 + t * 16;
        float4 f0 = *(const float4*)(x + idx);
        float4 f1 = *(const float4*)(x + idx + 4);
        float4 f2 = *(const float4*)(x + idx + 8);
        float4 f3 = *(const float4*)(x + idx + 12);
        ushort8 u0, u1;
        u0[0]=f2bf(f0.x); u0[1]=f2bf(f0.y); u0[2]=f2bf(f0.z); u0[3]=f2bf(f0.w);
        u0[4]=f2bf(f1.x); u0[5]=f2bf(f1.y); u0[6]=f2bf(f1.z); u0[7]=f2bf(f1.w);
        u1[0]=f2bf(f2.x); u1[1]=f2bf(f2.y); u1[2]=f2bf(f2.z); u1[3]=f2bf(f2.w);
        u1[4]=f2bf(f3.x); u1[5]=f2bf(f3.y); u1[6]=f2bf(f3.z); u1[7]=f2bf(f3.w);
        *(ushort8*)(xb + idx)     = u0;
        *(ushort8*)(xb + idx + 8) = u1;
    } else if (b < HPB2) {
        int i = (b - HPB1) * 256 + t;
        int n = i / IN_F, k = i % IN_F;
        float v;
        if (n < HID_F)            v = Wl0[k * HID_F + n];
        else if (n < 2 * HID_F)   v = Wh0[k * HID_F + (n - HID_F)];
        else                      v = Wm0[k * HID_F + (n - 2 * HID_F)];
        W0t[i] = f2bf(v);
    } else {
        int i = (b - HPB2) * 256 + t;
        int n = i / HID_F, kp = i % HID_F;
        // k-dim permuted to match hbuf's permuted layout: feat = g*64 + q*16 + c
        int k = ((kp >> 6) << 6) + ((kp & 3) << 4) + ((kp >> 2) & 15);
        float v;
        if (n < OUT_F)            v = Wl1[k * OUT_F + n];
        else if (n < 2 * OUT_F)   v = Wh1[k * OUT_F + (n - OUT_F)];
        else                      v = Wm1[k * OUT_F + (n - 2 * OUT_F)];
        W1t[i] = f2bf(v);
    }
}

// ------- scanseg: in-place segHist -> per-segment offsets; local rowPtr + dinv + blkTot -------

__global__ __launch_bounds__(256) void k_scanseg(
        unsigned* __restrict__ segHist, int* __restrict__ rowPtr,
        float* __restrict__ dinv, int* __restrict__ blkTot) {
    __shared__ int s[256];
    int t = threadIdx.x;
    int w = blockIdx.x * 256 + t;    // packed word = nodes 2w, 2w+1
    int cum0 = 0, cum1 = 0;
    if (w < NWORD) {
        for (int sg = 0; sg < SEG; ++sg) {
            size_t idx = (size_t)sg * NWORD + w;
            unsigned h = segHist[idx];
            segHist[idx] = ((unsigned)cum1 << 16) | (unsigned)cum0;  // offset-before
            cum0 += (int)(h & 0xffffu);
            cum1 += (int)(h >> 16);
        }
    }
    int deg0 = cum0, deg1 = cum1;
    int pair = deg0 + deg1;
    s[t] = pair; __syncthreads();
    for (int d = 1; d < 256; d <<= 1) {
        int x = (t >= d) ? s[t - d] : 0;
        __syncthreads();
        s[t] += x;
        __syncthreads();
    }
    int basep = s[t] - pair;   // exclusive prefix within block
    if (w < NWORD) {
        rowPtr[2 * w]     = basep;
        rowPtr[2 * w + 1] = basep + deg0;
        dinv[2 * w]     = 1.0f / (1.0f + (float)deg0);
        dinv[2 * w + 1] = 1.0f / (1.0f + (float)deg1);
    }
    if (t == 255) blkTot[blockIdx.x] = s[255];
}

__global__ void k_scan2(int* __restrict__ blk) {
    __shared__ int s[256];
    int t = threadIdx.x;
    int v = (t < WB) ? blk[t] : 0;
    s[t] = v; __syncthreads();
    for (int d = 1; d < 256; d <<= 1) {
        int x = (t >= d) ? s[t - d] : 0;
        __syncthreads();
        s[t] += x;
        __syncthreads();
    }
    if (t < WB) blk[t] = s[t] - v;
}

__global__ void k_scan3(const int* __restrict__ blkOff, int* __restrict__ rowPtr) {
    int t = threadIdx.x;
    int gid = blockIdx.x * 256 + t;
    if (gid < N_NODES) rowPtr[gid] += blkOff[gid >> 9];   // 512 nodes per scanseg block
    if (gid == 0) rowPtr[N_NODES] = N_EDGES;
}

// ---------------- bf16 MFMA GEMM + optional fused atomic-free CSR-fill ----------------
// tile 128x128, BK=32, 4 waves (2x2).
// EPI=0 (GEMM1): bf16 split write cols [0,nsplit)->C0(ld0), rest->C1(ld1);
//                plus fp8 byte store to Cq[gm*nsplit+gn] for gn<nsplit.
// EPI=1 (GEMM0): Hs (bf16 perm), Hq (fp8 perm), HmP (bf16 perm).
//   permuted pos within 64-col group: pos = col*4 + n  <->  feat = n*16 + col

#define BKP 40   // 32 + 8 pad

template<int EPI>
__global__ __launch_bounds__(256) void k_gemm_fill(
        const unsigned short* __restrict__ A, const unsigned short* __restrict__ Bt,
        unsigned short* __restrict__ C0, int ld0,
        unsigned short* __restrict__ C1, int ld1, int nsplit,
        unsigned char* __restrict__ Cq,
        unsigned short* __restrict__ Hs, unsigned char* __restrict__ Hq,
        unsigned short* __restrict__ HmP,
        int M, int N, int K, int nxt,
        const unsigned* __restrict__ rc, const unsigned short* __restrict__ rank,
        const int* __restrict__ rowPtr, const unsigned short* __restrict__ segOff,
        unsigned short* __restrict__ colIdx) {
    __shared__ unsigned short As[128 * BKP];
    __shared__ unsigned short Bs[128 * BKP];
    int tid  = threadIdx.x;

    if ((int)blockIdx.x >= nxt) {
        int fid = (blockIdx.x - nxt) * gridDim.y + blockIdx.y;
        int e = fid * 256 + tid;
        if (e < N_EDGES) {
            unsigned x = rc[e];
            int r = (int)(x >> 16);
            int seg = e / EPB;
            int pos = rowPtr[r] + (int)segOff[(size_t)seg * N_NODES + r] + (int)rank[e];
            colIdx[pos] = (unsigned short)(x & 0xffffu);
        }
        return;
    }

    int lane = tid & 63, wid = tid >> 6;
    int wr = wid >> 1, wc = wid & 1;
    int bm = blockIdx.y * 128, bn = blockIdx.x * 128;

    int srow = tid >> 1;
    int scol = (tid & 1) * 16;

    int garow = min(bm + srow, M - 1);
    int gbrow = min(bn + srow, N - 1);

    f32x4 acc[4][4];
#pragma unroll
    for (int m = 0; m < 4; ++m)
#pragma unroll
        for (int n = 0; n < 4; ++n)
            acc[m][n] = (f32x4)(0.0f);

    int kg = (lane >> 4) * 8;
    int rA = wr * 64 + (lane & 15);
    int rB = wc * 64 + (lane & 15);

    for (int k0 = 0; k0 < K; k0 += 32) {
        {
            const unsigned short* src = A + (size_t)garow * K + k0 + scol;
            *(ushort8*)&As[srow * BKP + scol]     = *(const ushort8*)(src);
            *(ushort8*)&As[srow * BKP + scol + 8] = *(const ushort8*)(src + 8);
        }
        {
            const unsigned short* src = Bt + (size_t)gbrow * K + k0 + scol;
            *(ushort8*)&Bs[srow * BKP + scol]     = *(const ushort8*)(src);
            *(ushort8*)&Bs[srow * BKP + scol + 8] = *(const ushort8*)(src + 8);
        }
        __syncthreads();

        bf16x8 a[4], b[4];
#pragma unroll
        for (int m = 0; m < 4; ++m)
            a[m] = __builtin_bit_cast(bf16x8, *(const ushort8*)&As[(rA + m * 16) * BKP + kg]);
#pragma unroll
        for (int n = 0; n < 4; ++n)
            b[n] = __builtin_bit_cast(bf16x8, *(const ushort8*)&Bs[(rB + n * 16) * BKP + kg]);
#pragma unroll
        for (int m = 0; m < 4; ++m)
#pragma unroll
            for (int n = 0; n < 4; ++n)
                acc[m][n] = __builtin_amdgcn_mfma_f32_16x16x32_bf16(a[m], b[n], acc[m][n], 0, 0, 0);
        __syncthreads();
    }

    int col  = lane & 15;
    int rsub = (lane >> 4) * 4;

    if (EPI == 0) {
#pragma unroll
        for (int m = 0; m < 4; ++m) {
            int gm0 = bm + wr * 64 + m * 16 + rsub;
#pragma unroll
            for (int n = 0; n < 4; ++n) {
                int gn = bn + wc * 64 + n * 16 + col;
                if (gn >= N) continue;
#pragma unroll
                for (int j = 0; j < 4; ++j) {
                    int gm = gm0 + j;
                    if (gm >= M) continue;
                    float v = acc[m][n][j];
                    unsigned short b = f2bf(v);
                    if (gn < nsplit) {
                        C0[(size_t)gm * ld0 + gn] = b;
                        int pk = __builtin_amdgcn_cvt_pk_fp8_f32(v, v, 0, false);
                        Cq[(size_t)gm * nsplit + gn] = (unsigned char)(pk & 0xff);
                    } else {
                        C1[(size_t)gm * ld1 + (gn - nsplit)] = b;
                    }
                }
            }
        }
    } else {
        // permuted writes; this thread covers pos base = bn + wc*64 + col*4
#pragma unroll
        for (int m = 0; m < 4; ++m) {
            int gm0 = bm + wr * 64 + m * 16 + rsub;
#pragma unroll
            for (int j = 0; j < 4; ++j) {
                int gm = gm0 + j;
                if (gm >= M) continue;
                float v0 = acc[m][0][j], v1 = acc[m][1][j];
                float v2 = acc[m][2][j], v3 = acc[m][3][j];
                ushort4v o;
                o[0] = f2bf(v0); o[1] = f2bf(v1); o[2] = f2bf(v2); o[3] = f2bf(v3);
                if (bn < 256) {
                    int pos = bn + wc * 64 + col * 4;
                    *(ushort4v*)&Hs[(size_t)gm * 256 + pos] = o;
                    int pk = 0;
                    pk = __builtin_amdgcn_cvt_pk_fp8_f32(v0, v1, pk, false);
                    pk = __builtin_amdgcn_cvt_pk_fp8_f32(v2, v3, pk, true);
                    *(unsigned*)&Hq[(size_t)gm * 256 + pos] = (unsigned)pk;
                } else {
                    int pos = wc * 64 + col * 4;
                    *(ushort4v*)&HmP[(size_t)gm * 128 + pos] = o;
                }
            }
        }
    }
}

// ---------------- layer 0: wave-per-node, shfl-decoupled fp8 gather + ACM epilogue ----------------
// Hq fp8 perm [256 B/row]; Hs bf16 perm [256]; HmP bf16 perm [128].
// Neighbor list loaded once per 64-chunk (1 coalesced read); indices broadcast via shfl.

__global__ __launch_bounds__(256) void k_layer0(
        const unsigned short* __restrict__ Hs, const unsigned char* __restrict__ Hq,
        const unsigned short* __restrict__ HmP,
        const int* __restrict__ rowPtr, const unsigned short* __restrict__ colIdx,
        const float* __restrict__ dinv,
        const float* __restrict__ al, const float* __restrict__ ah,
        const float* __restrict__ am, const float* __restrict__ att,
        unsigned short* __restrict__ hout) {
    int lane = threadIdx.x & 63;
    int i = blockIdx.x * 4 + (threadIdx.x >> 6);

    int p0 = rfl(rowPtr[i]);
    int p1 = rfl(rowPtr[i + 1]);
    int deg = p1 - p0;
    float a0 = 0.f, a1 = 0.f, a2 = 0.f, a3 = 0.f;
    int off4 = lane * 4;

    auto gath = [&](int js) -> unsigned {
        return *(const unsigned*)(Hq + ((size_t)(unsigned)js << 8) + off4);
    };
    auto addw = [&](unsigned w) {
        f32x2 d0 = __builtin_amdgcn_cvt_pk_f32_fp8((int)w, false);
        f32x2 d1 = __builtin_amdgcn_cvt_pk_f32_fp8((int)w, true);
        a0 += d0.x; a1 += d0.y; a2 += d1.x; a3 += d1.y;
    };

    for (int c = 0; c < deg; c += 64) {
        int rem = deg - c; if (rem > 64) rem = 64;
        int mycol = (int)colIdx[p0 + c + (lane < rem ? lane : 0)];
        int q = 0;
        for (; q + 7 < rem; q += 8) {
            int j0 = rfl(__shfl(mycol, q + 0));
            int j1 = rfl(__shfl(mycol, q + 1));
            int j2 = rfl(__shfl(mycol, q + 2));
            int j3 = rfl(__shfl(mycol, q + 3));
            int j4 = rfl(__shfl(mycol, q + 4));
            int j5 = rfl(__shfl(mycol, q + 5));
            int j6 = rfl(__shfl(mycol, q + 6));
            int j7 = rfl(__shfl(mycol, q + 7));
            unsigned w0 = gath(j0), w1 = gath(j1), w2 = gath(j2), w3 = gath(j3);
            unsigned w4 = gath(j4), w5 = gath(j5), w6 = gath(j6), w7 = gath(j7);
            addw(w0); addw(w1); addw(w2); addw(w3);
            addw(w4); addw(w5); addw(w6); addw(w7);
        }
        for (; q < rem; ++q) {
            int j = rfl(__shfl(mycol, q));
            addw(gath(j));
        }
    }

    uint2 sv = *(const uint2*)(Hs + (size_t)i * 256 + off4);   // 4 bf16 self vals
    float s0 = bflo(sv.x), s1 = bfhi(sv.x), s2 = bflo(sv.y), s3 = bfhi(sv.y);
    float di = dinv[i];
    float l0 = di * (s0 + a0), l1 = di * (s1 + a1);
    float l2 = di * (s2 + a2), l3 = di * (s3 + a3);

    float ol0 = fmaxf(l0, 0.f), ol1 = fmaxf(l1, 0.f);
    float ol2 = fmaxf(l2, 0.f), ol3 = fmaxf(l3, 0.f);
    float oh0 = fmaxf(s0 - l0, 0.f), oh1 = fmaxf(s1 - l1, 0.f);
    float oh2 = fmaxf(s2 - l2, 0.f), oh3 = fmaxf(s3 - l3, 0.f);

    int c0 = ((lane >> 4) << 6) + (lane & 15);   // true feat of q=0

    float om0 = 0.f, om1 = 0.f, om2 = 0.f, om3 = 0.f;
    float prA, prM = 0.f;
    if (lane < 32) {
        uint2 hv = *(const uint2*)(HmP + (size_t)i * 128 + off4);
        om0 = fmaxf(bflo(hv.x), 0.f); om1 = fmaxf(bfhi(hv.x), 0.f);
        om2 = fmaxf(bflo(hv.y), 0.f); om3 = fmaxf(bfhi(hv.y), 0.f);
        prA = ol0 * al[c0] + ol1 * al[c0 + 16] + ol2 * al[c0 + 32] + ol3 * al[c0 + 48];
        prM = om0 * am[c0] + om1 * am[c0 + 16] + om2 * am[c0 + 32] + om3 * am[c0 + 48];
    } else {
        int ch = c0 - 128;
        prA = oh0 * ah[ch] + oh1 * ah[ch + 16] + oh2 * ah[ch + 32] + oh3 * ah[ch + 48];
    }

#pragma unroll
    for (int d = 1; d < 32; d <<= 1) prA += __shfl_xor(prA, d);
#pragma unroll
    for (int d = 1; d < 32; d <<= 1) prM += __shfl_xor(prM, d);
    float g0 = __shfl(prA, 0);
    float g1 = __shfl(prA, 32);
    float g2 = __shfl(prM, 0);

    float sg0 = sigmoidf_(g0), sg1 = sigmoidf_(g1), sg2 = sigmoidf_(g2);
    const float inv3 = (1.0f / 3.0f);
    float e0 = (sg0 * att[0] + sg1 * att[3] + sg2 * att[6]) * inv3;
    float e1 = (sg0 * att[1] + sg1 * att[4] + sg2 * att[7]) * inv3;
    float e2 = (sg0 * att[2] + sg1 * att[5] + sg2 * att[8]) * inv3;
    float mx = fmaxf(e0, fmaxf(e1, e2));
    float x0 = expf(e0 - mx), x1 = expf(e1 - mx), x2 = expf(e2 - mx);
    float inv = 1.0f / (x0 + x1 + x2);
    float c0f = 3.0f * inv * x0, c1f = 3.0f * inv * x1, c2f = 3.0f * inv * x2;

    int src = lane | 32;
    float th0 = __shfl(oh0, src), th1 = __shfl(oh1, src);
    float th2 = __shfl(oh2, src), th3 = __shfl(oh3, src);

    if (lane < 32) {
        // hbuf permuted: pos p = lane*4+q -> true feat c_q (matches W1t k-perm)
        ushort4v o;
        o[0] = f2bf(c0f * ol0 + c1f * th0 + c2f * om0);
        o[1] = f2bf(c0f * ol1 + c1f * th1 + c2f * om1);
        o[2] = f2bf(c0f * ol2 + c1f * th2 + c2f * om2);
        o[3] = f2bf(c0f * ol3 + c1f * th3 + c2f * om3);
        *(ushort4v*)&hout[(size_t)i * 128 + off4] = o;
    }
}

// ---------------- layer 1: wave-per-node, shfl-decoupled fp8 gather + ACM epilogue ----------------
// H1q fp8 plain [80 B/row]; H1g bf16 plain [80] (self); H1m bf16 [40].
// lane l<20 covers feats 4l..4l+3; inactive lanes clamp their load offset (stay in-row).

__global__ __launch_bounds__(256) void k_layer1(
        const unsigned short* __restrict__ H1g, const unsigned char* __restrict__ H1q,
        const unsigned short* __restrict__ H1m,
        const int* __restrict__ rowPtr, const unsigned short* __restrict__ colIdx,
        const float* __restrict__ dinv,
        const float* __restrict__ al, const float* __restrict__ ah,
        const float* __restrict__ am, const float* __restrict__ att,
        float* __restrict__ out) {
    int lane = threadIdx.x & 63;
    int i = blockIdx.x * 4 + (threadIdx.x >> 6);

    int p0 = rfl(rowPtr[i]);
    int p1 = rfl(rowPtr[i + 1]);
    int deg = p1 - p0;
    float a0 = 0.f, a1 = 0.f, a2 = 0.f, a3 = 0.f;
    bool active = lane < 20;
    int off4 = lane * 4;
    int offc = active ? off4 : 0;    // clamp: inactive lanes load safely in-row

    auto gath = [&](int js) -> unsigned {
        return *(const unsigned*)(H1q + (size_t)((unsigned)js * 80u) + offc);
    };
    auto addw = [&](unsigned w) {
        f32x2 d0 = __builtin_amdgcn_cvt_pk_f32_fp8((int)w, false);
        f32x2 d1 = __builtin_amdgcn_cvt_pk_f32_fp8((int)w, true);
        a0 += d0.x; a1 += d0.y; a2 += d1.x; a3 += d1.y;
    };

    for (int c = 0; c < deg; c += 64) {
        int rem = deg - c; if (rem > 64) rem = 64;
        int mycol = (int)colIdx[p0 + c + (lane < rem ? lane : 0)];
        int q = 0;
        for (; q + 7 < rem; q += 8) {
            int j0 = rfl(__shfl(mycol, q + 0));
            int j1 = rfl(__shfl(mycol, q + 1));
            int j2 = rfl(__shfl(mycol, q + 2));
            int j3 = rfl(__shfl(mycol, q + 3));
            int j4 = rfl(__shfl(mycol, q + 4));
            int j5 = rfl(__shfl(mycol, q + 5));
            int j6 = rfl(__shfl(mycol, q + 6));
            int j7 = rfl(__shfl(mycol, q + 7));
            unsigned w0 = gath(j0), w1 = gath(j1), w2 = gath(j2), w3 = gath(j3);
            unsigned w4 = gath(j4), w5 = gath(j5), w6 = gath(j6), w7 = gath(j7);
            addw(w0); addw(w1); addw(w2); addw(w3);
            addw(w4); addw(w5); addw(w6); addw(w7);
        }
        for (; q < rem; ++q) {
            int j = rfl(__shfl(mycol, q));
            addw(gath(j));
        }
    }

    float s0 = 0.f, s1 = 0.f, s2 = 0.f, s3 = 0.f;
    if (active) {
        uint2 sv = *(const uint2*)(H1g + (size_t)i * 80 + off4);  // 4 bf16 self
        s0 = bflo(sv.x); s1 = bfhi(sv.x); s2 = bflo(sv.y); s3 = bfhi(sv.y);
    }
    float di = dinv[i];
    float l0 = di * (s0 + a0), l1 = di * (s1 + a1);
    float l2 = di * (s2 + a2), l3 = di * (s3 + a3);

    float ol0 = fmaxf(l0, 0.f), ol1 = fmaxf(l1, 0.f);
    float ol2 = fmaxf(l2, 0.f), ol3 = fmaxf(l3, 0.f);
    float oh0 = fmaxf(s0 - l0, 0.f), oh1 = fmaxf(s1 - l1, 0.f);
    float oh2 = fmaxf(s2 - l2, 0.f), oh3 = fmaxf(s3 - l3, 0.f);

    float om0 = 0.f, om1 = 0.f, om2 = 0.f, om3 = 0.f;
    float r0 = 0.f, r1 = 0.f, r2 = 0.f;
    if (lane < 10) {
        uint2 hv = *(const uint2*)(H1m + (size_t)i * 40 + off4);
        om0 = fmaxf(bflo(hv.x), 0.f); om1 = fmaxf(bfhi(hv.x), 0.f);
        om2 = fmaxf(bflo(hv.y), 0.f); om3 = fmaxf(bfhi(hv.y), 0.f);
        float4 alv = *(const float4*)(al + off4);
        float4 amv = *(const float4*)(am + off4);
        r0 = ol0 * alv.x + ol1 * alv.y + ol2 * alv.z + ol3 * alv.w;
        r2 = om0 * amv.x + om1 * amv.y + om2 * amv.z + om3 * amv.w;
    } else if (lane < 20) {
        float4 ahv = *(const float4*)(ah + (off4 - 40));
        r1 = oh0 * ahv.x + oh1 * ahv.y + oh2 * ahv.z + oh3 * ahv.w;
    }

#pragma unroll
    for (int d = 1; d < 64; d <<= 1) r0 += __shfl_xor(r0, d);
#pragma unroll
    for (int d = 1; d < 64; d <<= 1) r1 += __shfl_xor(r1, d);
#pragma unroll
    for (int d = 1; d < 64; d <<= 1) r2 += __shfl_xor(r2, d);

    float sg0 = sigmoidf_(r0), sg1 = sigmoidf_(r1), sg2 = sigmoidf_(r2);
    const float inv3 = (1.0f / 3.0f);
    float e0 = (sg0 * att[0] + sg1 * att[3] + sg2 * att[6]) * inv3;
    float e1 = (sg0 * att[1] + sg1 * att[4] + sg2 * att[7]) * inv3;
    float e2 = (sg0 * att[2] + sg1 * att[5] + sg2 * att[8]) * inv3;
    float mx = fmaxf(e0, fmaxf(e1, e2));
    float x0 = expf(e0 - mx), x1 = expf(e1 - mx), x2 = expf(e2 - mx);
    float inv = 1.0f / (x0 + x1 + x2);
    float c0 = 3.0f * inv * x0, c1 = 3.0f * inv * x1, c2 = 3.0f * inv * x2;

    // oh for output feat f (=4l+k) lives on lane l+10, same k
    int src = (lane + 10) & 63;
    float th0 = __shfl(oh0, src), th1 = __shfl(oh1, src);
    float th2 = __shfl(oh2, src), th3 = __shfl(oh3, src);

    if (lane < 10) {
        float4 o;
        o.x = c0 * ol0 + c1 * th0 + c2 * om0;
        o.y = c0 * ol1 + c1 * th1 + c2 * om1;
        o.z = c0 * ol2 + c1 * th2 + c2 * om2;
        o.w = c0 * ol3 + c1 * th3 + c2 * om3;
        *(float4*)&out[(size_t)i * 40 + off4] = o;
    }
}

// ---------------- launch ----------------

extern "C" void kernel_launch(void* const* d_in, const int* in_sizes, int n_in,
                              void* d_out, int out_size, void* d_ws, size_t ws_size,
                              hipStream_t stream) {
    const float* x    = (const float*)d_in[0];
    const int*   ei   = (const int*)d_in[1];
    const float* Wl0  = (const float*)d_in[2];
    const float* Wh0  = (const float*)d_in[3];
    const float* Wm0  = (const float*)d_in[4];
    const float* al0  = (const float*)d_in[5];
    const float* ah0  = (const float*)d_in[6];
    const float* am0  = (const float*)d_in[7];
    const float* att0 = (const float*)d_in[8];
    const float* Wl1  = (const float*)d_in[9];
    const float* Wh1  = (const float*)d_in[10];
    const float* Wm1  = (const float*)d_in[11];
    const float* al1  = (const float*)d_in[12];
    const float* ah1  = (const float*)d_in[13];
    const float* am1  = (const float*)d_in[14];
    const float* att1 = (const float*)d_in[15];
    float* out = (float*)d_out;

    char* ws = (char*)d_ws;
    size_t off = 0;
    auto alloc = [&](size_t bytes) -> char* {
        char* p = ws + off;
        off += (bytes + 255) & ~(size_t)255;
        return p;
    };
    int*      rowPtr  = (int*)     alloc((size_t)(N_NODES + 1) * 4);
    int*      blkTot  = (int*)     alloc(256 * 4);
    unsigned* segHist = (unsigned*)alloc((size_t)SEG * NWORD * 4);   // 12.8 MB
    unsigned short* rank   = (unsigned short*)alloc((size_t)N_EDGES * 2);
    unsigned*       rc     = (unsigned*)      alloc((size_t)N_EDGES * 4);
    unsigned short* colIdx = (unsigned short*)alloc((size_t)N_EDGES * 2 + 256);
    float* dinv   = (float*)alloc((size_t)N_NODES * 4);
    unsigned short* W0t  = (unsigned short*)alloc((size_t)W0N * IN_F * 2);
    unsigned short* W1t  = (unsigned short*)alloc((size_t)W1N * HID_F * 2);
    unsigned short* xb   = (unsigned short*)alloc((size_t)N_NODES * IN_F * 2);
    unsigned short* Hs   = (unsigned short*)alloc((size_t)N_NODES * 256 * 2);
    unsigned char*  Hq   = (unsigned char*) alloc((size_t)N_NODES * 256);
    unsigned short* HmP  = (unsigned short*)alloc((size_t)N_NODES * 128 * 2);
    unsigned short* H1g  = (unsigned short*)alloc((size_t)N_NODES * 80 * 2);
    unsigned char*  H1q  = (unsigned char*) alloc((size_t)N_NODES * 80 + 256);  // +pad
    unsigned short* H1m  = (unsigned short*)alloc((size_t)N_NODES * 40 * 2);
    unsigned short* hbuf = (unsigned short*)alloc((size_t)N_NODES * HID_F * 2);

    // 1. fused: segmented LDS histogram | x->bf16 | W packs
    k_hp<<<HPREPB, 256, 0, stream>>>(ei, segHist, rank, rc,
                                     x, xb, Wl0, Wh0, Wm0, W0t,
                                     Wl1, Wh1, Wm1, W1t);
    // 2. segment-offset scan + local rowPtr + dinv
    k_scanseg<<<WB, 256, 0, stream>>>(segHist, rowPtr, dinv, blkTot);
    // 3-4. block-offset scan + apply
    k_scan2<<<1, 256, 0, stream>>>(blkTot);
    k_scan3<<<NB, 256, 0, stream>>>(blkTot, rowPtr);
    // 5. GEMM0 (layer-0 epilogue: Hs/Hq/HmP) with fused atomic-free CSR fill
    {
        dim3 grid(3 + 8, (N_NODES + 127) / 128);
        k_gemm_fill<1><<<grid, 256, 0, stream>>>(xb, W0t,
                                                 nullptr, 0, nullptr, 0, 0, nullptr,
                                                 Hs, Hq, HmP,
                                                 N_NODES, W0N, IN_F, 3,
                                                 rc, rank, rowPtr,
                                                 (const unsigned short*)segHist, colIdx);
    }
    // 6. layer-0 aggregate + epilogue
    k_layer0<<<N_NODES / 4, 256, 0, stream>>>(Hs, Hq, HmP, rowPtr, colIdx, dinv,
                                              al0, ah0, am0, att0, hbuf);
    // 7. GEMM1 (bf16 H1g/H1m + fp8 H1q)
    {
        dim3 grid(1, (N_NODES + 127) / 128);
        k_gemm_fill<0><<<grid, 256, 0, stream>>>(hbuf, W1t,
                                                 H1g, 80, H1m, 40, 80, H1q,
                                                 nullptr, nullptr, nullptr,
                                                 N_NODES, W1N, HID_F, 1,
                                                 nullptr, nullptr, nullptr, nullptr, nullptr);
    }
    // 8. layer-1 aggregate + epilogue
    k_layer1<<<N_NODES / 4, 256, 0, stream>>>(H1g, H1q, H1m, rowPtr, colIdx, dinv,
                                              al1, ah1, am1, att1, out);
}